// Round 1
// baseline (18683.386 us; speedup 1.0000x reference)
//
#include <hip/hip_runtime.h>

// InverseFoldingModel: 3-layer message-passing GNN, f32 baseline.
// N=20000 nodes, K=30 neighbors, H=E=128, edge-in=240, L=3, A=20.

#define NN   20000
#define KNN  30
#define H    128
#define EIN  240
#define NL   3
#define AOUT 20
#define CIN  384   // 2H + E
#define EPSV 1e-5f

// ---------------- init kernels ----------------

__global__ __launch_bounds__(256) void node_init_kernel(
    const float* __restrict__ nf, const float* __restrict__ Wn,
    const float* __restrict__ bn, float* __restrict__ nodes)
{
  int tid = blockIdx.x * 256 + threadIdx.x;       // n*H + h
  if (tid >= NN * H) return;
  int n = tid >> 7, h = tid & (H - 1);
  float acc = bn[h];
  #pragma unroll
  for (int i = 0; i < 6; ++i)
    acc = fmaf(nf[n * 6 + i], Wn[i * H + h], acc);
  nodes[tid] = acc;
}

__global__ __launch_bounds__(256) void edge_init_kernel(
    const float* __restrict__ ef, const float* __restrict__ We,
    const float* __restrict__ be, float* __restrict__ edges)
{
  // 8 rows of (N*K, 240) per block -> (N*K, 128)
  __shared__ __align__(16) float xs[8 * EIN];
  int r0 = blockIdx.x * 8;
  int t = threadIdx.x;
  for (int idx = t; idx < 8 * EIN; idx += 256) {
    int r = idx / EIN, i = idx - r * EIN;
    xs[idx] = ef[(r0 + r) * EIN + i];
  }
  __syncthreads();
  int e = t & (H - 1), rg = t >> 7;               // rg = 0/1, 4 rows each
  float acc[4] = {0.f, 0.f, 0.f, 0.f};
  for (int i = 0; i < EIN; ++i) {
    float w = We[i * H + e];
    #pragma unroll
    for (int r = 0; r < 4; ++r)
      acc[r] = fmaf(xs[(rg * 4 + r) * EIN + i], w, acc[r]);
  }
  float bv = be[e];
  #pragma unroll
  for (int r = 0; r < 4; ++r)
    edges[(r0 + rg * 4 + r) * H + e] = acc[r] + bv;
}

// ---------------- shared helpers ----------------

// Stage concat input rows for node n into LDS:
// xbuf = [ src(128) | nbr[k=0..29][128] | edge[k=0..29][128] ]
__device__ __forceinline__ void stage_x(
    const float* __restrict__ nodes, const float* __restrict__ edges,
    const int* __restrict__ knn, int n, int t, float* xbuf)
{
  if (t < H) xbuf[t] = nodes[n * H + t];
  for (int idx = t; idx < KNN * H; idx += 256) {
    int k = idx >> 7, c = idx & (H - 1);
    int nb = knn[n * KNN + k];
    xbuf[H + idx] = nodes[nb * H + c];
    xbuf[H + KNN * H + idx] = edges[(n * KNN + k) * H + c];
  }
}

// First MLP matmul for all K rows of one node.
// Thread t: cols {jj, jj+64}, rows k = grp + 4m (m<8, guard covers k<30).
// s0/s1 = shared src-segment contribution; acc0/acc1[m] = per-k nbr+edge part.
__device__ __forceinline__ void mm1(
    const float* __restrict__ W1, int t, const float* xbuf,
    float& s0, float& s1, float* acc0, float* acc1)
{
  const int jj = t & 63;
  const int grp = t >> 6;
  const float* Wc0 = W1 + jj;
  const float* Wc1 = W1 + jj + 64;

  s0 = 0.f; s1 = 0.f;
  for (int i = 0; i < H; i += 4) {
    float4 xv = *(const float4*)(xbuf + i);
    s0 = fmaf(xv.x, Wc0[(i + 0) * H], s0);
    s0 = fmaf(xv.y, Wc0[(i + 1) * H], s0);
    s0 = fmaf(xv.z, Wc0[(i + 2) * H], s0);
    s0 = fmaf(xv.w, Wc0[(i + 3) * H], s0);
    s1 = fmaf(xv.x, Wc1[(i + 0) * H], s1);
    s1 = fmaf(xv.y, Wc1[(i + 1) * H], s1);
    s1 = fmaf(xv.z, Wc1[(i + 2) * H], s1);
    s1 = fmaf(xv.w, Wc1[(i + 3) * H], s1);
  }
  #pragma unroll
  for (int m = 0; m < 8; ++m) { acc0[m] = 0.f; acc1[m] = 0.f; }

  for (int i = 0; i < H; i += 4) {
    float w0[4], w1[4], u0[4], u1[4];
    #pragma unroll
    for (int d = 0; d < 4; ++d) {
      w0[d] = Wc0[(H + i + d) * H];       // nbr rows 128..255
      w1[d] = Wc1[(H + i + d) * H];
      u0[d] = Wc0[(2 * H + i + d) * H];   // edge rows 256..383
      u1[d] = Wc1[(2 * H + i + d) * H];
    }
    #pragma unroll
    for (int m = 0; m < 8; ++m) {
      int k = grp + (m << 2);
      if (m < 7 || grp < 2) {             // wave-uniform guard (k < 30)
        float4 xn = *(const float4*)(xbuf + H + k * H + i);
        float4 xe = *(const float4*)(xbuf + H + KNN * H + k * H + i);
        acc0[m] = fmaf(xn.x, w0[0], acc0[m]);
        acc0[m] = fmaf(xn.y, w0[1], acc0[m]);
        acc0[m] = fmaf(xn.z, w0[2], acc0[m]);
        acc0[m] = fmaf(xn.w, w0[3], acc0[m]);
        acc1[m] = fmaf(xn.x, w1[0], acc1[m]);
        acc1[m] = fmaf(xn.y, w1[1], acc1[m]);
        acc1[m] = fmaf(xn.z, w1[2], acc1[m]);
        acc1[m] = fmaf(xn.w, w1[3], acc1[m]);
        acc0[m] = fmaf(xe.x, u0[0], acc0[m]);
        acc0[m] = fmaf(xe.y, u0[1], acc0[m]);
        acc0[m] = fmaf(xe.z, u0[2], acc0[m]);
        acc0[m] = fmaf(xe.w, u0[3], acc0[m]);
        acc1[m] = fmaf(xe.x, u1[0], acc1[m]);
        acc1[m] = fmaf(xe.y, u1[1], acc1[m]);
        acc1[m] = fmaf(xe.z, u1[2], acc1[m]);
        acc1[m] = fmaf(xe.w, u1[3], acc1[m]);
      }
    }
  }
}

// ---------------- per-layer kernels ----------------

// A: agg[n] = sum_k relu(msg_in @ W1 + b1) @ W2 + K*b2   (second linear hoisted out of k-sum)
__global__ __launch_bounds__(256) void msg_agg_kernel(
    const float* __restrict__ nodes, const float* __restrict__ edges,
    const int* __restrict__ knn, const float* __restrict__ W1,
    const float* __restrict__ b1, const float* __restrict__ W2,
    const float* __restrict__ b2, float* __restrict__ agg)
{
  __shared__ __align__(16) float xbuf[(1 + 2 * KNN) * H];
  __shared__ __align__(16) float hpart[4][H];
  __shared__ __align__(16) float hsum[H];
  int n = blockIdx.x, t = threadIdx.x;
  stage_x(nodes, edges, knn, n, t, xbuf);
  __syncthreads();

  float s0, s1, acc0[8], acc1[8];
  mm1(W1, t, xbuf, s0, s1, acc0, acc1);

  int jj = t & 63, grp = t >> 6;
  float b10 = b1[jj], b11 = b1[jj + 64];
  float hs0 = 0.f, hs1 = 0.f;
  #pragma unroll
  for (int m = 0; m < 8; ++m) {
    if (m < 7 || grp < 2) {
      hs0 += fmaxf(s0 + acc0[m] + b10, 0.f);
      hs1 += fmaxf(s1 + acc1[m] + b11, 0.f);
    }
  }
  hpart[grp][jj] = hs0;
  hpart[grp][jj + 64] = hs1;
  __syncthreads();
  if (t < H)
    hsum[t] = hpart[0][t] + hpart[1][t] + hpart[2][t] + hpart[3][t];
  __syncthreads();
  if (t < H) {
    float acc = 0.f;
    for (int j = 0; j < H; j += 4) {
      float4 hv = *(const float4*)(hsum + j);
      acc = fmaf(hv.x, W2[(j + 0) * H + t], acc);
      acc = fmaf(hv.y, W2[(j + 1) * H + t], acc);
      acc = fmaf(hv.z, W2[(j + 2) * H + t], acc);
      acc = fmaf(hv.w, W2[(j + 3) * H + t], acc);
    }
    agg[n * H + t] = acc + (float)KNN * b2[t];
  }
}

// B: nodes[n] = LN(nodes[n] + MLP2(concat(nodes[n], agg[n])))
__global__ __launch_bounds__(128) void node_upd_kernel(
    float* __restrict__ nodes, const float* __restrict__ agg,
    const float* __restrict__ W1, const float* __restrict__ b1,
    const float* __restrict__ W2, const float* __restrict__ b2,
    const float* __restrict__ g, const float* __restrict__ bb)
{
  __shared__ __align__(16) float x[2 * H];
  __shared__ __align__(16) float h[H];
  __shared__ float red[2][2];
  int n = blockIdx.x, t = threadIdx.x;
  x[t] = nodes[n * H + t];
  x[H + t] = agg[n * H + t];
  __syncthreads();
  float acc = 0.f;
  for (int i = 0; i < 2 * H; i += 4) {
    float4 xv = *(const float4*)(x + i);
    acc = fmaf(xv.x, W1[(i + 0) * H + t], acc);
    acc = fmaf(xv.y, W1[(i + 1) * H + t], acc);
    acc = fmaf(xv.z, W1[(i + 2) * H + t], acc);
    acc = fmaf(xv.w, W1[(i + 3) * H + t], acc);
  }
  h[t] = fmaxf(acc + b1[t], 0.f);
  __syncthreads();
  float acc2 = 0.f;
  for (int j = 0; j < H; j += 4) {
    float4 hv = *(const float4*)(h + j);
    acc2 = fmaf(hv.x, W2[(j + 0) * H + t], acc2);
    acc2 = fmaf(hv.y, W2[(j + 1) * H + t], acc2);
    acc2 = fmaf(hv.z, W2[(j + 2) * H + t], acc2);
    acc2 = fmaf(hv.w, W2[(j + 3) * H + t], acc2);
  }
  float y = x[t] + acc2 + b2[t];
  float sum = y, sq = y * y;
  #pragma unroll
  for (int off = 1; off < 64; off <<= 1) {
    sum += __shfl_xor(sum, off);
    sq  += __shfl_xor(sq, off);
  }
  int wv = t >> 6;
  if ((t & 63) == 0) { red[wv][0] = sum; red[wv][1] = sq; }
  __syncthreads();
  float tot = red[0][0] + red[1][0];
  float tsq = red[0][1] + red[1][1];
  float mean = tot * (1.f / (float)H);
  float var  = tsq * (1.f / (float)H) - mean * mean;
  nodes[n * H + t] = (y - mean) * rsqrtf(var + EPSV) * g[t] + bb[t];
}

// C: edges[n,k] = LN(edges[n,k] + MLP2(concat(src, nbr, edges[n,k])))
__global__ __launch_bounds__(256) void edge_upd_kernel(
    const float* __restrict__ nodes, float* __restrict__ edges,
    const int* __restrict__ knn, const float* __restrict__ W1,
    const float* __restrict__ b1, const float* __restrict__ W2,
    const float* __restrict__ b2, const float* __restrict__ g,
    const float* __restrict__ bb)
{
  __shared__ __align__(16) float xbuf[(1 + 2 * KNN) * H];
  __shared__ __align__(16) float hbuf[KNN * H];
  __shared__ float red[2][2][2];
  int n = blockIdx.x, t = threadIdx.x;
  stage_x(nodes, edges, knn, n, t, xbuf);
  __syncthreads();

  float s0, s1, acc0[8], acc1[8];
  mm1(W1, t, xbuf, s0, s1, acc0, acc1);

  int jj = t & 63, grp = t >> 6;
  float b10 = b1[jj], b11 = b1[jj + 64];
  #pragma unroll
  for (int m = 0; m < 8; ++m) {
    int k = grp + (m << 2);
    if (m < 7 || grp < 2) {
      hbuf[k * H + jj]      = fmaxf(s0 + acc0[m] + b10, 0.f);
      hbuf[k * H + jj + 64] = fmaxf(s1 + acc1[m] + b11, 0.f);
    }
  }
  __syncthreads();

  // second matmul + residual + LayerNorm, 2 groups of 128 threads, 15 rows each
  int j2 = t & (H - 1);
  int kg = t >> 7;
  int wv = (t >> 6) & 1;
  float b2v = b2[j2], gv = g[j2], bbv = bb[j2];
  for (int kk = 0; kk < 15; ++kk) {
    int k = kg * 15 + kk;
    float acc = 0.f;
    for (int j = 0; j < H; j += 4) {
      float4 hv = *(const float4*)(hbuf + k * H + j);
      acc = fmaf(hv.x, W2[(j + 0) * H + j2], acc);
      acc = fmaf(hv.y, W2[(j + 1) * H + j2], acc);
      acc = fmaf(hv.z, W2[(j + 2) * H + j2], acc);
      acc = fmaf(hv.w, W2[(j + 3) * H + j2], acc);
    }
    float y = xbuf[H + KNN * H + k * H + j2] + acc + b2v;
    float sum = y, sq = y * y;
    #pragma unroll
    for (int off = 1; off < 64; off <<= 1) {
      sum += __shfl_xor(sum, off);
      sq  += __shfl_xor(sq, off);
    }
    if ((t & 63) == 0) { red[kg][wv][0] = sum; red[kg][wv][1] = sq; }
    __syncthreads();
    float tot = red[kg][0][0] + red[kg][1][0];
    float tsq = red[kg][0][1] + red[kg][1][1];
    float mean = tot * (1.f / (float)H);
    float var  = tsq * (1.f / (float)H) - mean * mean;
    edges[(n * KNN + k) * H + j2] = (y - mean) * rsqrtf(var + EPSV) * gv + bbv;
    __syncthreads();
  }
}

// ---------------- output ----------------

__global__ __launch_bounds__(64) void out_kernel(
    const float* __restrict__ nodes, const float* __restrict__ Wout,
    const float* __restrict__ bout, float* __restrict__ out)
{
  __shared__ float x[H];
  int n = blockIdx.x, t = threadIdx.x;
  x[t] = nodes[n * H + t];
  x[64 + t] = nodes[n * H + 64 + t];
  __syncthreads();
  if (t < AOUT) {
    float acc = bout[t];
    for (int hh = 0; hh < H; ++hh)
      acc = fmaf(x[hh], Wout[hh * AOUT + t], acc);
    out[n * AOUT + t] = acc;
  }
}

// ---------------- launch ----------------

extern "C" void kernel_launch(void* const* d_in, const int* in_sizes, int n_in,
                              void* d_out, int out_size, void* d_ws, size_t ws_size,
                              hipStream_t stream) {
  const float* nf    = (const float*)d_in[0];
  const float* ef    = (const float*)d_in[1];
  const int*   knn   = (const int*)  d_in[2];
  const float* Wn    = (const float*)d_in[3];
  const float* bn    = (const float*)d_in[4];
  const float* We    = (const float*)d_in[5];
  const float* be    = (const float*)d_in[6];
  const float* mW1   = (const float*)d_in[7];
  const float* mb1   = (const float*)d_in[8];
  const float* mW2   = (const float*)d_in[9];
  const float* mb2   = (const float*)d_in[10];
  const float* nW1   = (const float*)d_in[11];
  const float* nb1   = (const float*)d_in[12];
  const float* nW2   = (const float*)d_in[13];
  const float* nb2   = (const float*)d_in[14];
  const float* eW1   = (const float*)d_in[15];
  const float* eb1   = (const float*)d_in[16];
  const float* eW2   = (const float*)d_in[17];
  const float* eb2   = (const float*)d_in[18];
  const float* gn    = (const float*)d_in[19];
  const float* bnrm  = (const float*)d_in[20];
  const float* ge    = (const float*)d_in[21];
  const float* benrm = (const float*)d_in[22];
  const float* Wout  = (const float*)d_in[23];
  const float* bout  = (const float*)d_in[24];
  float* out = (float*)d_out;

  float* ws    = (float*)d_ws;
  float* nodes = ws;                 // N*H
  float* agg   = ws + NN * H;        // N*H
  float* edges = ws + 2 * NN * H;    // N*K*H  (307 MB)

  node_init_kernel<<<(NN * H + 255) / 256, 256, 0, stream>>>(nf, Wn, bn, nodes);
  edge_init_kernel<<<(NN * KNN) / 8, 256, 0, stream>>>(ef, We, be, edges);

  for (int l = 0; l < NL; ++l) {
    msg_agg_kernel<<<NN, 256, 0, stream>>>(
        nodes, edges, knn,
        mW1 + l * CIN * H, mb1 + l * H, mW2 + l * H * H, mb2 + l * H, agg);
    node_upd_kernel<<<NN, 128, 0, stream>>>(
        nodes, agg,
        nW1 + l * 2 * H * H, nb1 + l * H, nW2 + l * H * H, nb2 + l * H,
        gn + l * H, bnrm + l * H);
    edge_upd_kernel<<<NN, 256, 0, stream>>>(
        nodes, edges, knn,
        eW1 + l * CIN * H, eb1 + l * H, eW2 + l * H * H, eb2 + l * H,
        ge + l * H, benrm + l * H);
  }
  out_kernel<<<NN, 64, 0, stream>>>(nodes, Wout, bout, out);
}

// Round 2
// 3470.499 us; speedup vs baseline: 5.3835x; 5.3835x over previous
//
#include <hip/hip_runtime.h>

// InverseFoldingModel: 3-layer message-passing GNN, MFMA (bf16 hi/lo 3-term) version.
// N=20000 nodes, K=30 neighbors, H=E=128, edge-in=240, L=3, A=20.

#define NN   20000
#define KNN  30
#define H    128
#define EIN  240
#define NL   3
#define AOUT 20
#define CIN  384   // 2H + E
#define EPSV 1e-5f

typedef unsigned short u16;
typedef unsigned int   u32;
typedef float f32x16 __attribute__((ext_vector_type(16)));
typedef short s16x8  __attribute__((ext_vector_type(8)));
typedef short s16x4  __attribute__((ext_vector_type(4)));

// D = A*B + D, 32x32x16 bf16. Inline asm avoids builtin operand-type ambiguity.
#define MFMA32(acc, a, b) \
  asm("v_mfma_f32_32x32x16_bf16 %0, %1, %2, %0" : "+v"(acc) : "v"(a), "v"(b))

__device__ __forceinline__ u16 bh(float x) {           // f32 -> bf16 (RNE)
  u32 u = __float_as_uint(x);
  u += 0x7fffu + ((u >> 16) & 1u);
  return (u16)(u >> 16);
}
__device__ __forceinline__ float hf(u16 h) { return __uint_as_float(((u32)h) << 16); }

// XOR-swizzled LDS indices (u16 units). A rows: 512 u16 (32 logical k-chunks of 16,
// each chunk = 16 hi + 16 lo). P rows: 256 u16. Swizzle: byte ^= (row&7)<<4.
__device__ __forceinline__ int axi(int row, int off) { return (row * 512 + off) ^ ((row & 7) << 3); }
__device__ __forceinline__ int pxi(int row, int off) { return (row * 256 + off) ^ ((row & 7) << 3); }

// write 4 consecutive logical-k elements (k&15 in {0,4,8,12}) as hi4+lo4
__device__ __forceinline__ void wrA4(u16* A, int row, int off, float4 v) {
  u16 h0 = bh(v.x), h1 = bh(v.y), h2 = bh(v.z), h3 = bh(v.w);
  s16x4 hv = { (short)h0, (short)h1, (short)h2, (short)h3 };
  s16x4 lv = { (short)bh(v.x - hf(h0)), (short)bh(v.y - hf(h1)),
               (short)bh(v.z - hf(h2)), (short)bh(v.w - hf(h3)) };
  *(s16x4*)(A + axi(row, off))      = hv;
  *(s16x4*)(A + axi(row, off + 16)) = lv;
}

// ---------------- weight repack: W (nS*16 x 128 f32) -> fragment-ordered hi/lo bf16 ----------------
// pk layout: [coltile c<4][chunk s<nS][h<2][lane<64][8 u16]; lane l holds
// W[s*16 + (l>>5)*8 + i][c*32 + (l&31)].
__global__ __launch_bounds__(256) void repack_w(
    const float* __restrict__ W, u16* __restrict__ pk, int nS)
{
  int s = blockIdx.x;
  int t = threadIdx.x;
  int c = t >> 6, l = t & 63;
  int col = c * 32 + (l & 31);
  int kb  = s * 16 + (l >> 5) * 8;
  size_t base = ((size_t)(c * nS + s) * 2) * 512 + l * 8;
  #pragma unroll
  for (int i = 0; i < 8; ++i) {
    float v = W[(size_t)(kb + i) * H + col];
    u16 hi = bh(v);
    pk[base + i]       = hi;
    pk[base + 512 + i] = bh(v - hf(hi));
  }
}

// ---------------- init ----------------

__global__ __launch_bounds__(256) void node_init_kernel(
    const float* __restrict__ nf, const float* __restrict__ Wn,
    const float* __restrict__ bn, float* __restrict__ nodes)
{
  int tid = blockIdx.x * 256 + threadIdx.x;
  if (tid >= NN * H) return;
  int n = tid >> 7, h = tid & (H - 1);
  float acc = bn[h];
  #pragma unroll
  for (int i = 0; i < 6; ++i)
    acc = fmaf(nf[n * 6 + i], Wn[i * H + h], acc);
  nodes[tid] = acc;
}

// edges = ef @ We + be, 32 rows/block via MFMA (K=240 -> 15 chunks)
__global__ __launch_bounds__(256) void edge_init_mfma(
    const float* __restrict__ ef, const u16* __restrict__ pkWe,
    const float* __restrict__ be, float* __restrict__ edges)
{
  __shared__ __align__(16) u16 A[32 * 512];
  int r0 = blockIdx.x * 32, t = threadIdx.x;
  for (int u = t; u < 1920; u += 256) {           // 32 rows x 60 float4
    int r = u / 60, q = u - r * 60;
    int k = q * 4;
    float4 v = *(const float4*)(ef + (size_t)(r0 + r) * EIN + k);
    wrA4(A, r, (k >> 4) * 32 + (k & 15), v);
  }
  __syncthreads();
  int w = t >> 6, l = t & 63;
  int lane31 = l & 31, half = l >> 5;
  float bev = be[w * 32 + lane31];
  f32x16 acc;
  #pragma unroll
  for (int r = 0; r < 16; ++r) acc[r] = bev;
  #pragma unroll
  for (int s = 0; s < 15; ++s) {
    s16x8 ah = *(const s16x8*)(A + axi(lane31, s * 32 + half * 8));
    s16x8 al = *(const s16x8*)(A + axi(lane31, s * 32 + 16 + half * 8));
    const u16* pb = pkWe + (size_t)((w * 15 + s) * 2) * 512 + l * 8;
    s16x8 bhv = *(const s16x8*)(pb);
    s16x8 blv = *(const s16x8*)(pb + 512);
    MFMA32(acc, ah, bhv);
    MFMA32(acc, al, bhv);
    MFMA32(acc, ah, blv);
  }
  #pragma unroll
  for (int r = 0; r < 16; ++r) {
    int row = (r & 3) + 8 * (r >> 2) + 4 * half;
    edges[(size_t)(r0 + row) * H + w * 32 + lane31] = acc[r];
  }
}

// ---------------- shared pieces ----------------

// stage A rows for node n: k<128 -> gathered neighbor node row, k>=128 -> edge row.
// rows 30,31 zeroed.
__device__ __forceinline__ void stage_gather(
    const float* __restrict__ nodes, const float* __restrict__ edges,
    const int* __restrict__ knn, int n, int t, u16* A)
{
  if (t < 240) {
    int r = t >> 3, kb = t & 7;
    const float* src;
    if (kb < 4) src = nodes + (size_t)knn[n * KNN + r] * H + kb * 32;
    else        src = edges + ((size_t)n * KNN + r) * H + (kb - 4) * 32;
    int k0 = kb * 32;
    #pragma unroll
    for (int q = 0; q < 8; ++q) {
      float4 v = *(const float4*)(src + q * 4);
      int k = k0 + q * 4;
      wrA4(A, r, (k >> 4) * 32 + (k & 15), v);
    }
  } else {
    int r = 30 + (t & 1);
    int sg = (t - 240) >> 1;
    s16x4 z = {0, 0, 0, 0};
    #pragma unroll
    for (int j = 0; j < 64; j += 4)
      *(s16x4*)(A + axi(r, sg * 64 + j)) = z;
  }
}

// MLP1: acc = sp (src@W1src + b1, broadcast over rows) + A @ W1bc, K=256 -> 16 chunks
__device__ __forceinline__ f32x16 mlp1_mfma(
    const u16* A, const u16* __restrict__ pk, float spv, int l)
{
  int lane31 = l & 31, half = l >> 5;
  f32x16 acc;
  #pragma unroll
  for (int r = 0; r < 16; ++r) acc[r] = spv;
  #pragma unroll
  for (int s = 0; s < 16; ++s) {
    s16x8 ah = *(const s16x8*)(A + axi(lane31, s * 32 + half * 8));
    s16x8 al = *(const s16x8*)(A + axi(lane31, s * 32 + 16 + half * 8));
    const u16* pb = pk + (size_t)(s * 2) * 512 + l * 8;
    s16x8 bhv = *(const s16x8*)(pb);
    s16x8 blv = *(const s16x8*)(pb + 512);
    MFMA32(acc, ah, bhv);
    MFMA32(acc, al, bhv);
    MFMA32(acc, ah, blv);
  }
  return acc;
}

// sp = nodes @ W[0:128] + b  (per-node src contribution, f32)
__global__ __launch_bounds__(256) void sp_kernel(
    const float* __restrict__ nodes, const float* __restrict__ W,
    const float* __restrict__ b, float* __restrict__ sp)
{
  __shared__ __align__(16) float xl[2][H];
  int n0 = blockIdx.x * 2, t = threadIdx.x;
  int row = t >> 7, col = t & (H - 1);
  xl[row][col] = nodes[(size_t)(n0 + row) * H + col];
  __syncthreads();
  float acc = b[col];
  for (int k = 0; k < H; k += 4) {
    float4 xv = *(const float4*)(&xl[row][k]);
    acc = fmaf(xv.x, W[(k + 0) * H + col], acc);
    acc = fmaf(xv.y, W[(k + 1) * H + col], acc);
    acc = fmaf(xv.z, W[(k + 2) * H + col], acc);
    acc = fmaf(xv.w, W[(k + 3) * H + col], acc);
  }
  sp[(size_t)(n0 + row) * H + col] = acc;
}

// ---------------- per-layer kernels ----------------

__global__ __launch_bounds__(256) void msg_agg_mfma(
    const float* __restrict__ nodes, const float* __restrict__ edges,
    const int* __restrict__ knn, const float* __restrict__ sp,
    const u16* __restrict__ pkW1, const float* __restrict__ W2,
    const float* __restrict__ b2, float* __restrict__ agg)
{
  __shared__ __align__(16) u16 A[32 * 512];
  __shared__ __align__(16) float hsum[H];
  int n = blockIdx.x, t = threadIdx.x;
  stage_gather(nodes, edges, knn, n, t, A);
  __syncthreads();
  int w = t >> 6, l = t & 63;
  int lane31 = l & 31, half = l >> 5;
  float spv = sp[(size_t)n * H + w * 32 + lane31];
  f32x16 acc = mlp1_mfma(A, pkW1 + (size_t)(w * 16) * 1024, spv, l);
  // relu + sum over k rows (mask pad rows 30,31 = regs 14,15 on half=1)
  float ss = 0.f;
  #pragma unroll
  for (int r = 0; r < 16; ++r) {
    float v = fmaxf(acc[r], 0.f);
    if (r >= 14) v = half ? 0.f : v;
    ss += v;
  }
  ss += __shfl_xor(ss, 32);
  if (l < 32) hsum[w * 32 + l] = ss;
  __syncthreads();
  if (t < H) {
    float a2 = 0.f;
    for (int k = 0; k < H; k += 4) {
      float4 hv = *(const float4*)(hsum + k);
      a2 = fmaf(hv.x, W2[(k + 0) * H + t], a2);
      a2 = fmaf(hv.y, W2[(k + 1) * H + t], a2);
      a2 = fmaf(hv.z, W2[(k + 2) * H + t], a2);
      a2 = fmaf(hv.w, W2[(k + 3) * H + t], a2);
    }
    agg[(size_t)n * H + t] = a2 + (float)KNN * b2[t];
  }
}

__global__ __launch_bounds__(128) void node_upd_kernel(
    float* __restrict__ nodes, const float* __restrict__ agg,
    const float* __restrict__ W1, const float* __restrict__ b1,
    const float* __restrict__ W2, const float* __restrict__ b2,
    const float* __restrict__ g, const float* __restrict__ bb)
{
  __shared__ __align__(16) float x[2 * H];
  __shared__ __align__(16) float h[H];
  __shared__ float red[2][2];
  int n = blockIdx.x, t = threadIdx.x;
  x[t] = nodes[(size_t)n * H + t];
  x[H + t] = agg[(size_t)n * H + t];
  __syncthreads();
  float acc = 0.f;
  for (int i = 0; i < 2 * H; i += 4) {
    float4 xv = *(const float4*)(x + i);
    acc = fmaf(xv.x, W1[(i + 0) * H + t], acc);
    acc = fmaf(xv.y, W1[(i + 1) * H + t], acc);
    acc = fmaf(xv.z, W1[(i + 2) * H + t], acc);
    acc = fmaf(xv.w, W1[(i + 3) * H + t], acc);
  }
  h[t] = fmaxf(acc + b1[t], 0.f);
  __syncthreads();
  float acc2 = 0.f;
  for (int j = 0; j < H; j += 4) {
    float4 hv = *(const float4*)(h + j);
    acc2 = fmaf(hv.x, W2[(j + 0) * H + t], acc2);
    acc2 = fmaf(hv.y, W2[(j + 1) * H + t], acc2);
    acc2 = fmaf(hv.z, W2[(j + 2) * H + t], acc2);
    acc2 = fmaf(hv.w, W2[(j + 3) * H + t], acc2);
  }
  float y = x[t] + acc2 + b2[t];
  float sum = y, sq = y * y;
  #pragma unroll
  for (int off = 1; off < 64; off <<= 1) {
    sum += __shfl_xor(sum, off);
    sq  += __shfl_xor(sq, off);
  }
  int wv = t >> 6;
  if ((t & 63) == 0) { red[wv][0] = sum; red[wv][1] = sq; }
  __syncthreads();
  float tot = red[0][0] + red[1][0];
  float tsq = red[0][1] + red[1][1];
  float mean = tot * (1.f / (float)H);
  float var  = tsq * (1.f / (float)H) - mean * mean;
  nodes[(size_t)n * H + t] = (y - mean) * rsqrtf(var + EPSV) * g[t] + bb[t];
}

__global__ __launch_bounds__(256) void edge_upd_mfma(
    const float* __restrict__ nodes, float* __restrict__ edges,
    const int* __restrict__ knn, const float* __restrict__ sp,
    const u16* __restrict__ pkW1, const u16* __restrict__ pkW2,
    const float* __restrict__ b2, const float* __restrict__ g,
    const float* __restrict__ bb)
{
  __shared__ __align__(16) u16 A[32 * 512];
  __shared__ __align__(16) u16 P[32 * 256];
  __shared__ __align__(16) float O[32 * 132];
  __shared__ float red[2][2][2];
  int n = blockIdx.x, t = threadIdx.x;
  stage_gather(nodes, edges, knn, n, t, A);
  __syncthreads();
  int w = t >> 6, l = t & 63;
  int lane31 = l & 31, half = l >> 5;
  float spv = sp[(size_t)n * H + w * 32 + lane31];
  f32x16 acc = mlp1_mfma(A, pkW1 + (size_t)(w * 16) * 1024, spv, l);
  // P = relu(acc) as hi/lo into swizzled LDS (row-major over k=pcol)
  {
    int pcol = w * 32 + lane31;
    int offp = (pcol >> 4) * 32 + (pcol & 15);
    #pragma unroll
    for (int r = 0; r < 16; ++r) {
      int row = (r & 3) + 8 * (r >> 2) + 4 * half;
      float v = fmaxf(acc[r], 0.f);
      u16 hh = bh(v);
      P[pxi(row, offp)]      = hh;
      P[pxi(row, offp + 16)] = bh(v - hf(hh));
    }
  }
  __syncthreads();
  // MLP2: out2 = P @ W2 + b2, K=128 -> 8 chunks
  float b2v = b2[w * 32 + lane31];
  f32x16 a2;
  #pragma unroll
  for (int r = 0; r < 16; ++r) a2[r] = b2v;
  #pragma unroll
  for (int s = 0; s < 8; ++s) {
    s16x8 ah = *(const s16x8*)(P + pxi(lane31, s * 32 + half * 8));
    s16x8 al = *(const s16x8*)(P + pxi(lane31, s * 32 + 16 + half * 8));
    const u16* pb = pkW2 + (size_t)((w * 8 + s) * 2) * 512 + l * 8;
    s16x8 bhv = *(const s16x8*)(pb);
    s16x8 blv = *(const s16x8*)(pb + 512);
    MFMA32(a2, ah, bhv);
    MFMA32(a2, al, bhv);
    MFMA32(a2, ah, blv);
  }
  #pragma unroll
  for (int r = 0; r < 16; ++r) {
    int row = (r & 3) + 8 * (r >> 2) + 4 * half;
    O[row * 132 + w * 32 + lane31] = a2[r];
  }
  __syncthreads();
  // residual + LayerNorm (30 valid rows)
  int j2 = t & (H - 1);
  int kg = t >> 7;
  int wv = (t >> 6) & 1;
  float gv = g[j2], bbv = bb[j2];
  for (int kk = 0; kk < 15; ++kk) {
    int k = kg * 15 + kk;
    float y = edges[((size_t)n * KNN + k) * H + j2] + O[k * 132 + j2];
    float sum = y, sq = y * y;
    #pragma unroll
    for (int off = 1; off < 64; off <<= 1) {
      sum += __shfl_xor(sum, off);
      sq  += __shfl_xor(sq, off);
    }
    if ((t & 63) == 0) { red[kg][wv][0] = sum; red[kg][wv][1] = sq; }
    __syncthreads();
    float tot = red[kg][0][0] + red[kg][1][0];
    float tsq = red[kg][0][1] + red[kg][1][1];
    float mean = tot * (1.f / (float)H);
    float var  = tsq * (1.f / (float)H) - mean * mean;
    edges[((size_t)n * KNN + k) * H + j2] = (y - mean) * rsqrtf(var + EPSV) * gv + bbv;
    __syncthreads();
  }
}

// ---------------- output ----------------

__global__ __launch_bounds__(64) void out_kernel(
    const float* __restrict__ nodes, const float* __restrict__ Wout,
    const float* __restrict__ bout, float* __restrict__ out)
{
  __shared__ float x[H];
  int n = blockIdx.x, t = threadIdx.x;
  x[t] = nodes[(size_t)n * H + t];
  x[64 + t] = nodes[(size_t)n * H + 64 + t];
  __syncthreads();
  if (t < AOUT) {
    float acc = bout[t];
    for (int hh = 0; hh < H; ++hh)
      acc = fmaf(x[hh], Wout[hh * AOUT + t], acc);
    out[n * AOUT + t] = acc;
  }
}

// ---------------- launch ----------------

extern "C" void kernel_launch(void* const* d_in, const int* in_sizes, int n_in,
                              void* d_out, int out_size, void* d_ws, size_t ws_size,
                              hipStream_t stream) {
  const float* nf    = (const float*)d_in[0];
  const float* ef    = (const float*)d_in[1];
  const int*   knn   = (const int*)  d_in[2];
  const float* Wn    = (const float*)d_in[3];
  const float* bn    = (const float*)d_in[4];
  const float* We    = (const float*)d_in[5];
  const float* be    = (const float*)d_in[6];
  const float* mW1   = (const float*)d_in[7];
  const float* mb1   = (const float*)d_in[8];
  const float* mW2   = (const float*)d_in[9];
  const float* mb2   = (const float*)d_in[10];
  const float* nW1   = (const float*)d_in[11];
  const float* nb1   = (const float*)d_in[12];
  const float* nW2   = (const float*)d_in[13];
  const float* nb2   = (const float*)d_in[14];
  const float* eW1   = (const float*)d_in[15];
  const float* eb1   = (const float*)d_in[16];
  const float* eW2   = (const float*)d_in[17];
  const float* eb2   = (const float*)d_in[18];
  const float* gn    = (const float*)d_in[19];
  const float* bnrm  = (const float*)d_in[20];
  const float* ge    = (const float*)d_in[21];
  const float* benrm = (const float*)d_in[22];
  const float* Wout  = (const float*)d_in[23];
  const float* bout  = (const float*)d_in[24];
  float* out = (float*)d_out;

  float* ws    = (float*)d_ws;
  float* nodes = ws;                                   // N*H
  float* agg   = ws + (size_t)NN * H;                  // N*H
  float* sp    = ws + (size_t)2 * NN * H;              // N*H
  float* edges = ws + (size_t)3 * NN * H;              // N*K*H (307 MB)
  u16*   pk    = (u16*)(edges + (size_t)NN * KNN * H); // ~1.1 MB packed weights
  u16* pkWe = pk;                       // 4*15*2*512 = 61440
  u16* pkM1 = pkWe + 61440;             // 3 x 65536
  u16* pkE1 = pkM1 + 3 * 65536;        // 3 x 65536
  u16* pkE2 = pkE1 + 3 * 65536;        // 3 x 32768

  node_init_kernel<<<(NN * H + 255) / 256, 256, 0, stream>>>(nf, Wn, bn, nodes);
  repack_w<<<15, 256, 0, stream>>>(We, pkWe, 15);
  for (int l = 0; l < NL; ++l) {
    repack_w<<<16, 256, 0, stream>>>(mW1 + (size_t)l * CIN * H + 128 * H, pkM1 + l * 65536, 16);
    repack_w<<<16, 256, 0, stream>>>(eW1 + (size_t)l * CIN * H + 128 * H, pkE1 + l * 65536, 16);
    repack_w<<<8,  256, 0, stream>>>(eW2 + (size_t)l * H * H,             pkE2 + l * 32768, 8);
  }
  edge_init_mfma<<<NN * KNN / 32, 256, 0, stream>>>(ef, pkWe, be, edges);

  for (int l = 0; l < NL; ++l) {
    sp_kernel<<<NN / 2, 256, 0, stream>>>(nodes, mW1 + (size_t)l * CIN * H, mb1 + l * H, sp);
    msg_agg_mfma<<<NN, 256, 0, stream>>>(nodes, edges, knn, sp,
        pkM1 + l * 65536, mW2 + (size_t)l * H * H, mb2 + l * H, agg);
    node_upd_kernel<<<NN, 128, 0, stream>>>(nodes, agg,
        nW1 + (size_t)l * 2 * H * H, nb1 + l * H, nW2 + (size_t)l * H * H, nb2 + l * H,
        gn + l * H, bnrm + l * H);
    sp_kernel<<<NN / 2, 256, 0, stream>>>(nodes, eW1 + (size_t)l * CIN * H, eb1 + l * H, sp);
    edge_upd_mfma<<<NN, 256, 0, stream>>>(nodes, edges, knn, sp,
        pkE1 + l * 65536, pkE2 + l * 32768, eb2 + l * H, ge + l * H, benrm + l * H);
  }
  out_kernel<<<NN, 64, 0, stream>>>(nodes, Wout, bout, out);
}

// Round 4
// 3028.192 us; speedup vs baseline: 6.1698x; 1.1461x over previous
//
#include <hip/hip_runtime.h>

// InverseFoldingModel: 3-layer message-passing GNN, MFMA (bf16 hi/lo 3-term) version.
// R4: R2-verified dataflow + conflict-reduced staging; edge_upd tail = deferred-barrier
// LN with O aliased over A (no new reduction layout, no launch_bounds).

#define NN   20000
#define KNN  30
#define H    128
#define EIN  240
#define NL   3
#define AOUT 20
#define CIN  384   // 2H + E
#define EPSV 1e-5f

typedef unsigned short u16;
typedef unsigned int   u32;
typedef float f32x16 __attribute__((ext_vector_type(16)));
typedef short s16x8  __attribute__((ext_vector_type(8)));
typedef short s16x4  __attribute__((ext_vector_type(4)));

#define MFMA32(acc, a, b) \
  asm("v_mfma_f32_32x32x16_bf16 %0, %1, %2, %0" : "+v"(acc) : "v"(a), "v"(b))

__device__ __forceinline__ u16 bh(float x) {           // f32 -> bf16 (RNE)
  u32 u = __float_as_uint(x);
  u += 0x7fffu + ((u >> 16) & 1u);
  return (u16)(u >> 16);
}
__device__ __forceinline__ float hf(u16 h) { return __uint_as_float(((u32)h) << 16); }

// XOR-swizzled LDS indices (u16 units). Swizzle: byte ^= (row&7)<<4.
__device__ __forceinline__ int axi(int row, int off) { return (row * 512 + off) ^ ((row & 7) << 3); }
__device__ __forceinline__ int pxi(int row, int off) { return (row * 256 + off) ^ ((row & 7) << 3); }

// write 4 consecutive logical-k elements (k&15 in {0,4,8,12}) as hi4+lo4
__device__ __forceinline__ void wrA4(u16* A, int row, int off, float4 v) {
  u16 h0 = bh(v.x), h1 = bh(v.y), h2 = bh(v.z), h3 = bh(v.w);
  s16x4 hv = { (short)h0, (short)h1, (short)h2, (short)h3 };
  s16x4 lv = { (short)bh(v.x - hf(h0)), (short)bh(v.y - hf(h1)),
               (short)bh(v.z - hf(h2)), (short)bh(v.w - hf(h3)) };
  *(s16x4*)(A + axi(row, off))      = hv;
  *(s16x4*)(A + axi(row, off + 16)) = lv;
}

// ---------------- weight repack ----------------
// pk layout: [coltile c<4][chunk s<nS][h<2][lane<64][8 u16]; lane l holds
// W[s*16 + (l>>5)*8 + i][c*32 + (l&31)].
__global__ __launch_bounds__(256) void repack_w(
    const float* __restrict__ W, u16* __restrict__ pk, int nS)
{
  int s = blockIdx.x;
  int t = threadIdx.x;
  int c = t >> 6, l = t & 63;
  int col = c * 32 + (l & 31);
  int kb  = s * 16 + (l >> 5) * 8;
  size_t base = ((size_t)(c * nS + s) * 2) * 512 + l * 8;
  #pragma unroll
  for (int i = 0; i < 8; ++i) {
    float v = W[(size_t)(kb + i) * H + col];
    u16 hi = bh(v);
    pk[base + i]       = hi;
    pk[base + 512 + i] = bh(v - hf(hi));
  }
}

// ---------------- init ----------------

__global__ __launch_bounds__(256) void node_init_kernel(
    const float* __restrict__ nf, const float* __restrict__ Wn,
    const float* __restrict__ bn, float* __restrict__ nodes)
{
  int tid = blockIdx.x * 256 + threadIdx.x;
  if (tid >= NN * H) return;
  int n = tid >> 7, h = tid & (H - 1);
  float acc = bn[h];
  #pragma unroll
  for (int i = 0; i < 6; ++i)
    acc = fmaf(nf[n * 6 + i], Wn[i * H + h], acc);
  nodes[tid] = acc;
}

// edges = ef @ We + be, 32 rows/block via MFMA (K=240 -> 15 chunks)
__global__ __launch_bounds__(256) void edge_init_mfma(
    const float* __restrict__ ef, const u16* __restrict__ pkWe,
    const float* __restrict__ be, float* __restrict__ edges)
{
  __shared__ __align__(16) u16 A[32 * 512];
  int r0 = blockIdx.x * 32, t = threadIdx.x;
  for (int u = t; u < 1920; u += 256) {           // r = u&31: reduced store conflicts
    int r = u & 31, c = u >> 5;                   // c 0..59
    int k = c * 4;
    float4 v = *(const float4*)(ef + (size_t)(r0 + r) * EIN + k);
    wrA4(A, r, (k >> 4) * 32 + (k & 15), v);
  }
  __syncthreads();
  int w = t >> 6, l = t & 63;
  int lane31 = l & 31, half = l >> 5;
  float bev = be[w * 32 + lane31];
  f32x16 acc;
  #pragma unroll
  for (int r = 0; r < 16; ++r) acc[r] = bev;
  #pragma unroll
  for (int s = 0; s < 15; ++s) {
    s16x8 ah = *(const s16x8*)(A + axi(lane31, s * 32 + half * 8));
    s16x8 al = *(const s16x8*)(A + axi(lane31, s * 32 + 16 + half * 8));
    const u16* pb = pkWe + (size_t)((w * 15 + s) * 2) * 512 + l * 8;
    s16x8 bhv = *(const s16x8*)(pb);
    s16x8 blv = *(const s16x8*)(pb + 512);
    MFMA32(acc, ah, bhv);
    MFMA32(acc, al, bhv);
    MFMA32(acc, ah, blv);
  }
  #pragma unroll
  for (int r = 0; r < 16; ++r) {
    int row = (r & 3) + 8 * (r >> 2) + 4 * half;
    edges[(size_t)(r0 + row) * H + w * 32 + lane31] = acc[r];
  }
}

// ---------------- shared pieces ----------------

// stage A rows for node n. thread -> (row = t&31, kchunk = t>>5).
__device__ __forceinline__ void stage_gather(
    const float* __restrict__ nodes, const float* __restrict__ edges,
    const int* __restrict__ knn, int n, int t, u16* A)
{
  int r = t & 31, kb = t >> 5;          // kb 0..7
  bool valid = r < KNN;
  int rc = valid ? r : 0;
  const float* src;
  if (kb < 4) src = nodes + (size_t)knn[n * KNN + rc] * H + kb * 32;
  else        src = edges + ((size_t)n * KNN + rc) * H + (kb - 4) * 32;
  int k0 = kb * 32;
  #pragma unroll
  for (int q = 0; q < 8; ++q) {
    float4 v = {0.f, 0.f, 0.f, 0.f};
    if (valid) v = *(const float4*)(src + q * 4);
    int k = k0 + q * 4;
    wrA4(A, r, (k >> 4) * 32 + (k & 15), v);
  }
}

// MLP1: acc = sp (broadcast over rows) + A @ W1bc, K=256 -> 16 chunks
__device__ __forceinline__ f32x16 mlp1_mfma(
    const u16* A, const u16* __restrict__ pk, float spv, int l)
{
  int lane31 = l & 31, half = l >> 5;
  f32x16 acc;
  #pragma unroll
  for (int r = 0; r < 16; ++r) acc[r] = spv;
  #pragma unroll
  for (int s = 0; s < 16; ++s) {
    s16x8 ah = *(const s16x8*)(A + axi(lane31, s * 32 + half * 8));
    s16x8 al = *(const s16x8*)(A + axi(lane31, s * 32 + 16 + half * 8));
    const u16* pb = pk + (size_t)(s * 2) * 512 + l * 8;
    s16x8 bhv = *(const s16x8*)(pb);
    s16x8 blv = *(const s16x8*)(pb + 512);
    MFMA32(acc, ah, bhv);
    MFMA32(acc, al, bhv);
    MFMA32(acc, ah, blv);
  }
  return acc;
}

// sp = nodes @ W[0:128] + b
__global__ __launch_bounds__(256) void sp_kernel(
    const float* __restrict__ nodes, const float* __restrict__ W,
    const float* __restrict__ b, float* __restrict__ sp)
{
  __shared__ __align__(16) float xl[2][H];
  int n0 = blockIdx.x * 2, t = threadIdx.x;
  int row = t >> 7, col = t & (H - 1);
  xl[row][col] = nodes[(size_t)(n0 + row) * H + col];
  __syncthreads();
  float acc = b[col];
  for (int k = 0; k < H; k += 4) {
    float4 xv = *(const float4*)(&xl[row][k]);
    acc = fmaf(xv.x, W[(k + 0) * H + col], acc);
    acc = fmaf(xv.y, W[(k + 1) * H + col], acc);
    acc = fmaf(xv.z, W[(k + 2) * H + col], acc);
    acc = fmaf(xv.w, W[(k + 3) * H + col], acc);
  }
  sp[(size_t)(n0 + row) * H + col] = acc;
}

// ---------------- per-layer kernels ----------------

__global__ __launch_bounds__(256) void msg_agg_mfma(
    const float* __restrict__ nodes, const float* __restrict__ edges,
    const int* __restrict__ knn, const float* __restrict__ sp,
    const u16* __restrict__ pkW1, const float* __restrict__ W2,
    const float* __restrict__ b2, float* __restrict__ agg)
{
  __shared__ __align__(16) u16 A[32 * 512];
  __shared__ __align__(16) float hsum[H];
  int n = blockIdx.x, t = threadIdx.x;
  stage_gather(nodes, edges, knn, n, t, A);
  int w = t >> 6, l = t & 63;
  int lane31 = l & 31, half = l >> 5;
  float spv = sp[(size_t)n * H + w * 32 + lane31];
  __syncthreads();
  f32x16 acc = mlp1_mfma(A, pkW1 + (size_t)(w * 16) * 1024, spv, l);
  // relu + sum over k rows (mask pad rows 30,31 = regs 14,15 on half=1)
  float ss = 0.f;
  #pragma unroll
  for (int r = 0; r < 16; ++r) {
    float v = fmaxf(acc[r], 0.f);
    if (r >= 14) v = half ? 0.f : v;
    ss += v;
  }
  ss += __shfl_xor(ss, 32);
  if (l < 32) hsum[w * 32 + l] = ss;
  __syncthreads();
  if (t < H) {
    float a2 = 0.f;
    for (int k = 0; k < H; k += 4) {
      float4 hv = *(const float4*)(hsum + k);
      a2 = fmaf(hv.x, W2[(k + 0) * H + t], a2);
      a2 = fmaf(hv.y, W2[(k + 1) * H + t], a2);
      a2 = fmaf(hv.z, W2[(k + 2) * H + t], a2);
      a2 = fmaf(hv.w, W2[(k + 3) * H + t], a2);
    }
    agg[(size_t)n * H + t] = a2 + (float)KNN * b2[t];
  }
}

__global__ __launch_bounds__(128) void node_upd_kernel(
    float* __restrict__ nodes, const float* __restrict__ agg,
    const float* __restrict__ W1, const float* __restrict__ b1,
    const float* __restrict__ W2, const float* __restrict__ b2,
    const float* __restrict__ g, const float* __restrict__ bb)
{
  __shared__ __align__(16) float x[2 * H];
  __shared__ __align__(16) float h[H];
  __shared__ float red[2][2];
  int n = blockIdx.x, t = threadIdx.x;
  x[t] = nodes[(size_t)n * H + t];
  x[H + t] = agg[(size_t)n * H + t];
  __syncthreads();
  float acc = 0.f;
  for (int i = 0; i < 2 * H; i += 4) {
    float4 xv = *(const float4*)(x + i);
    acc = fmaf(xv.x, W1[(i + 0) * H + t], acc);
    acc = fmaf(xv.y, W1[(i + 1) * H + t], acc);
    acc = fmaf(xv.z, W1[(i + 2) * H + t], acc);
    acc = fmaf(xv.w, W1[(i + 3) * H + t], acc);
  }
  h[t] = fmaxf(acc + b1[t], 0.f);
  __syncthreads();
  float acc2 = 0.f;
  for (int j = 0; j < H; j += 4) {
    float4 hv = *(const float4*)(h + j);
    acc2 = fmaf(hv.x, W2[(j + 0) * H + t], acc2);
    acc2 = fmaf(hv.y, W2[(j + 1) * H + t], acc2);
    acc2 = fmaf(hv.z, W2[(j + 2) * H + t], acc2);
    acc2 = fmaf(hv.w, W2[(j + 3) * H + t], acc2);
  }
  float y = x[t] + acc2 + b2[t];
  float sum = y, sq = y * y;
  #pragma unroll
  for (int off = 1; off < 64; off <<= 1) {
    sum += __shfl_xor(sum, off);
    sq  += __shfl_xor(sq, off);
  }
  int wv = t >> 6;
  if ((t & 63) == 0) { red[wv][0] = sum; red[wv][1] = sq; }
  __syncthreads();
  float tot = red[0][0] + red[1][0];
  float tsq = red[0][1] + red[1][1];
  float mean = tot * (1.f / (float)H);
  float var  = tsq * (1.f / (float)H) - mean * mean;
  nodes[(size_t)n * H + t] = (y - mean) * rsqrtf(var + EPSV) * g[t] + bb[t];
}

__global__ __launch_bounds__(256) void edge_upd_mfma(
    const float* __restrict__ nodes, float* __restrict__ edges,
    const int* __restrict__ knn, const float* __restrict__ sp,
    const u16* __restrict__ pkW1, const u16* __restrict__ pkW2,
    const float* __restrict__ b2, const float* __restrict__ g,
    const float* __restrict__ bb)
{
  __shared__ __align__(16) u16 A[32 * 512];     // 32768 B; O aliases this after barrier 2
  __shared__ __align__(16) u16 P[32 * 256];     // 16384 B
  __shared__ float sumA[KNN][2], sqA[KNN][2];
  float* O = (float*)A;                         // 32 x 132 f32 = 16896 B <= 32768

  int n = blockIdx.x, t = threadIdx.x;
  stage_gather(nodes, edges, knn, n, t, A);
  int w = t >> 6, l = t & 63;
  int lane31 = l & 31, half = l >> 5;
  int col = w * 32 + lane31;
  float spv = sp[(size_t)n * H + col];
  __syncthreads();                              // 1: A staged
  f32x16 acc = mlp1_mfma(A, pkW1 + (size_t)(w * 16) * 1024, spv, l);
  // P = relu(acc) hi/lo into swizzled LDS (R2-verified mapping)
  {
    int offp = (col >> 4) * 32 + (col & 15);
    #pragma unroll
    for (int r = 0; r < 16; ++r) {
      int row = (r & 3) + 8 * (r >> 2) + 4 * half;
      float v = fmaxf(acc[r], 0.f);
      u16 hh = bh(v);
      P[pxi(row, offp)]      = hh;
      P[pxi(row, offp + 16)] = bh(v - hf(hh));
    }
  }
  // residual loads in MFMA layout (overlap with barrier/MLP2)
  float res[16];
  #pragma unroll
  for (int r = 0; r < 16; ++r) {
    int row = (r & 3) + 8 * (r >> 2) + 4 * half;
    int rowc = row < KNN ? row : 0;
    res[r] = edges[((size_t)n * KNN + rowc) * H + col];
  }
  __syncthreads();                              // 2: P ready, all A reads done
  // MLP2: a2 = P @ W2 + b2, K=128 -> 8 chunks
  float b2v = b2[col];
  f32x16 a2;
  #pragma unroll
  for (int r = 0; r < 16; ++r) a2[r] = b2v;
  #pragma unroll
  for (int s = 0; s < 8; ++s) {
    s16x8 ah = *(const s16x8*)(P + pxi(lane31, s * 32 + half * 8));
    s16x8 al = *(const s16x8*)(P + pxi(lane31, s * 32 + 16 + half * 8));
    const u16* pb = pkW2 + (size_t)((w * 8 + s) * 2) * 512 + l * 8;
    s16x8 bhv = *(const s16x8*)(pb);
    s16x8 blv = *(const s16x8*)(pb + 512);
    MFMA32(a2, ah, bhv);
    MFMA32(a2, al, bhv);
    MFMA32(a2, ah, blv);
  }
  // O = a2 + residual (R2-verified store mapping; O aliases dead A)
  #pragma unroll
  for (int r = 0; r < 16; ++r) {
    int row = (r & 3) + 8 * (r >> 2) + 4 * half;
    O[row * 132 + col] = a2[r] + res[r];
  }
  __syncthreads();                              // 3: O ready
  // LayerNorm tail: all partial sums first (no barrier in loop), then combine
  int j2 = t & (H - 1);
  int kg = t >> 7;
  int wv = (t >> 6) & 1;
  float yv[15];
  #pragma unroll
  for (int kk = 0; kk < 15; ++kk) {
    int k = kg * 15 + kk;
    float y = O[k * 132 + j2];
    yv[kk] = y;
    float s = y, q = y * y;
    #pragma unroll
    for (int off = 1; off < 64; off <<= 1) {
      s += __shfl_xor(s, off);
      q += __shfl_xor(q, off);
    }
    if ((t & 63) == 0) { sumA[k][wv] = s; sqA[k][wv] = q; }
  }
  __syncthreads();                              // 4: stats ready
  float gv = g[j2], bbv = bb[j2];
  #pragma unroll
  for (int kk = 0; kk < 15; ++kk) {
    int k = kg * 15 + kk;
    float tot = sumA[k][0] + sumA[k][1];
    float tsq = sqA[k][0] + sqA[k][1];
    float mean = tot * (1.f / (float)H);
    float var  = tsq * (1.f / (float)H) - mean * mean;
    edges[((size_t)n * KNN + k) * H + j2] = (yv[kk] - mean) * rsqrtf(var + EPSV) * gv + bbv;
  }
}

// ---------------- output ----------------

__global__ __launch_bounds__(64) void out_kernel(
    const float* __restrict__ nodes, const float* __restrict__ Wout,
    const float* __restrict__ bout, float* __restrict__ out)
{
  __shared__ float x[H];
  int n = blockIdx.x, t = threadIdx.x;
  x[t] = nodes[(size_t)n * H + t];
  x[64 + t] = nodes[(size_t)n * H + 64 + t];
  __syncthreads();
  if (t < AOUT) {
    float acc = bout[t];
    for (int hh = 0; hh < H; ++hh)
      acc = fmaf(x[hh], Wout[hh * AOUT + t], acc);
    out[n * AOUT + t] = acc;
  }
}

// ---------------- launch ----------------

extern "C" void kernel_launch(void* const* d_in, const int* in_sizes, int n_in,
                              void* d_out, int out_size, void* d_ws, size_t ws_size,
                              hipStream_t stream) {
  const float* nf    = (const float*)d_in[0];
  const float* ef    = (const float*)d_in[1];
  const int*   knn   = (const int*)  d_in[2];
  const float* Wn    = (const float*)d_in[3];
  const float* bn    = (const float*)d_in[4];
  const float* We    = (const float*)d_in[5];
  const float* be    = (const float*)d_in[6];
  const float* mW1   = (const float*)d_in[7];
  const float* mb1   = (const float*)d_in[8];
  const float* mW2   = (const float*)d_in[9];
  const float* mb2   = (const float*)d_in[10];
  const float* nW1   = (const float*)d_in[11];
  const float* nb1   = (const float*)d_in[12];
  const float* nW2   = (const float*)d_in[13];
  const float* nb2   = (const float*)d_in[14];
  const float* eW1   = (const float*)d_in[15];
  const float* eb1   = (const float*)d_in[16];
  const float* eW2   = (const float*)d_in[17];
  const float* eb2   = (const float*)d_in[18];
  const float* gn    = (const float*)d_in[19];
  const float* bnrm  = (const float*)d_in[20];
  const float* ge    = (const float*)d_in[21];
  const float* benrm = (const float*)d_in[22];
  const float* Wout  = (const float*)d_in[23];
  const float* bout  = (const float*)d_in[24];
  float* out = (float*)d_out;

  float* ws    = (float*)d_ws;
  float* nodes = ws;                                   // N*H
  float* agg   = ws + (size_t)NN * H;                  // N*H
  float* sp    = ws + (size_t)2 * NN * H;              // N*H
  float* edges = ws + (size_t)3 * NN * H;              // N*K*H (307 MB)
  u16*   pk    = (u16*)(edges + (size_t)NN * KNN * H); // ~1.1 MB packed weights
  u16* pkWe = pk;                       // 4*15*2*512 = 61440
  u16* pkM1 = pkWe + 61440;             // 3 x 65536
  u16* pkE1 = pkM1 + 3 * 65536;         // 3 x 65536
  u16* pkE2 = pkE1 + 3 * 65536;         // 3 x 32768

  node_init_kernel<<<(NN * H + 255) / 256, 256, 0, stream>>>(nf, Wn, bn, nodes);
  repack_w<<<15, 256, 0, stream>>>(We, pkWe, 15);
  for (int l = 0; l < NL; ++l) {
    repack_w<<<16, 256, 0, stream>>>(mW1 + (size_t)l * CIN * H + 128 * H, pkM1 + l * 65536, 16);
    repack_w<<<16, 256, 0, stream>>>(eW1 + (size_t)l * CIN * H + 128 * H, pkE1 + l * 65536, 16);
    repack_w<<<8,  256, 0, stream>>>(eW2 + (size_t)l * H * H,             pkE2 + l * 32768, 8);
  }
  edge_init_mfma<<<NN * KNN / 32, 256, 0, stream>>>(ef, pkWe, be, edges);

  for (int l = 0; l < NL; ++l) {
    sp_kernel<<<NN / 2, 256, 0, stream>>>(nodes, mW1 + (size_t)l * CIN * H, mb1 + l * H, sp);
    msg_agg_mfma<<<NN, 256, 0, stream>>>(nodes, edges, knn, sp,
        pkM1 + l * 65536, mW2 + (size_t)l * H * H, mb2 + l * H, agg);
    node_upd_kernel<<<NN, 128, 0, stream>>>(nodes, agg,
        nW1 + (size_t)l * 2 * H * H, nb1 + l * H, nW2 + (size_t)l * H * H, nb2 + l * H,
        gn + l * H, bnrm + l * H);
    sp_kernel<<<NN / 2, 256, 0, stream>>>(nodes, eW1 + (size_t)l * CIN * H, eb1 + l * H, sp);
    edge_upd_mfma<<<NN, 256, 0, stream>>>(nodes, edges, knn, sp,
        pkE1 + l * 65536, pkE2 + l * 32768, eb2 + l * H, ge + l * H, benrm + l * H);
  }
  out_kernel<<<NN, 64, 0, stream>>>(nodes, Wout, bout, out);
}

// Round 5
// 2887.520 us; speedup vs baseline: 6.4704x; 1.0487x over previous
//
#include <hip/hip_runtime.h>

// InverseFoldingModel: 3-layer message-passing GNN, MFMA (bf16 hi/lo 3-term).
// R5: packed bf16 hi/lo global storage for nodes/edges (convert-at-producer),
// copy-only staging, residual from LDS, 8-thread/row LN tail, cvt_pk packing.

#define NN   20000
#define KNN  30
#define H    128
#define EIN  240
#define NL   3
#define AOUT 20
#define CIN  384   // 2H + E
#define EPSV 1e-5f

typedef unsigned short u16;
typedef unsigned int   u32;
typedef float f32x16 __attribute__((ext_vector_type(16)));
typedef short s16x8  __attribute__((ext_vector_type(8)));
typedef short s16x4  __attribute__((ext_vector_type(4)));

#define MFMA32(acc, a, b) \
  asm("v_mfma_f32_32x32x16_bf16 %0, %1, %2, %0" : "+v"(acc) : "v"(a), "v"(b))

__device__ __forceinline__ u16 bh(float x) {           // f32 -> bf16 (RNE)
  u32 u = __float_as_uint(x);
  u += 0x7fffu + ((u >> 16) & 1u);
  return (u16)(u >> 16);
}
__device__ __forceinline__ float hf(u16 h) { return __uint_as_float(((u32)h) << 16); }
// packed 2x f32 -> 2x bf16 (lo16 = a, hi16 = b)
__device__ __forceinline__ u32 pk2(float a, float b) {
  u32 r; asm("v_cvt_pk_bf16_f32 %0, %1, %2" : "=v"(r) : "v"(a), "v"(b)); return r;
}

// packed-row layout: 128 elems -> 8 chunks x (16 hi u16 + 16 lo u16) = 256 u16
__device__ __forceinline__ int pko(int col) { return ((col >> 4) << 5) + (col & 15); }

// XOR-swizzled LDS indices (u16 units); swizzle: byte ^= (row&7)<<4
__device__ __forceinline__ int axi(int row, int off) { return (row * 512 + off) ^ ((row & 7) << 3); }
__device__ __forceinline__ int pxi(int row, int off) { return (row * 256 + off) ^ ((row & 7) << 3); }

// write 4 consecutive logical-k elements as hi4+lo4 (f32 source; edge_init only)
__device__ __forceinline__ void wrA4(u16* A, int row, int off, float4 v) {
  u16 h0 = bh(v.x), h1 = bh(v.y), h2 = bh(v.z), h3 = bh(v.w);
  s16x4 hv = { (short)h0, (short)h1, (short)h2, (short)h3 };
  s16x4 lv = { (short)bh(v.x - hf(h0)), (short)bh(v.y - hf(h1)),
               (short)bh(v.z - hf(h2)), (short)bh(v.w - hf(h3)) };
  *(s16x4*)(A + axi(row, off))      = hv;
  *(s16x4*)(A + axi(row, off + 16)) = lv;
}

// ---------------- weight repack ----------------
// pk layout: [coltile c<4][chunk s<nS][h<2][lane<64][8 u16]; lane l holds
// W[s*16 + (l>>5)*8 + i][c*32 + (l&31)].
__global__ __launch_bounds__(256) void repack_w(
    const float* __restrict__ W, u16* __restrict__ pk, int nS)
{
  int s = blockIdx.x;
  int t = threadIdx.x;
  int c = t >> 6, l = t & 63;
  int col = c * 32 + (l & 31);
  int kb  = s * 16 + (l >> 5) * 8;
  size_t base = ((size_t)(c * nS + s) * 2) * 512 + l * 8;
  #pragma unroll
  for (int i = 0; i < 8; ++i) {
    float v = W[(size_t)(kb + i) * H + col];
    u16 hi = bh(v);
    pk[base + i]       = hi;
    pk[base + 512 + i] = bh(v - hf(hi));
  }
}

// ---------------- init ----------------

__global__ __launch_bounds__(256) void node_init_kernel(
    const float* __restrict__ nf, const float* __restrict__ Wn,
    const float* __restrict__ bn, float* __restrict__ nodes,
    u16* __restrict__ nodes_pk)
{
  int tid = blockIdx.x * 256 + threadIdx.x;
  if (tid >= NN * H) return;
  int n = tid >> 7, h = tid & (H - 1);
  float acc = bn[h];
  #pragma unroll
  for (int i = 0; i < 6; ++i)
    acc = fmaf(nf[n * 6 + i], Wn[i * H + h], acc);
  nodes[tid] = acc;
  u16 hi = bh(acc);
  nodes_pk[(size_t)n * 256 + pko(h)]      = hi;
  nodes_pk[(size_t)n * 256 + pko(h) + 16] = bh(acc - hf(hi));
}

// edges = ef @ We + be, 32 rows/block via MFMA (K=240 -> 15 chunks), packed output
__global__ __launch_bounds__(256) void edge_init_mfma(
    const float* __restrict__ ef, const u16* __restrict__ pkWe,
    const float* __restrict__ be, u16* __restrict__ edges_pk)
{
  __shared__ __align__(16) u16 A[32 * 512];
  int r0 = blockIdx.x * 32, t = threadIdx.x;
  for (int u = t; u < 1920; u += 256) {
    int r = u & 31, c = u >> 5;                   // c 0..59
    int k = c * 4;
    float4 v = *(const float4*)(ef + (size_t)(r0 + r) * EIN + k);
    wrA4(A, r, (k >> 4) * 32 + (k & 15), v);
  }
  __syncthreads();
  int w = t >> 6, l = t & 63;
  int lane31 = l & 31, half = l >> 5;
  float bev = be[w * 32 + lane31];
  f32x16 acc;
  #pragma unroll
  for (int r = 0; r < 16; ++r) acc[r] = bev;
  #pragma unroll
  for (int s = 0; s < 15; ++s) {
    s16x8 ah = *(const s16x8*)(A + axi(lane31, s * 32 + half * 8));
    s16x8 al = *(const s16x8*)(A + axi(lane31, s * 32 + 16 + half * 8));
    const u16* pb = pkWe + (size_t)((w * 15 + s) * 2) * 512 + l * 8;
    s16x8 bhv = *(const s16x8*)(pb);
    s16x8 blv = *(const s16x8*)(pb + 512);
    MFMA32(acc, ah, bhv);
    MFMA32(acc, al, bhv);
    MFMA32(acc, ah, blv);
  }
  int col = w * 32 + lane31;
  #pragma unroll
  for (int r = 0; r < 16; ++r) {
    int row = (r & 3) + 8 * (r >> 2) + 4 * half;
    float v = acc[r];
    u16 hi = bh(v);
    size_t base = (size_t)(r0 + row) * 256 + pko(col);
    edges_pk[base]      = hi;
    edges_pk[base + 16] = bh(v - hf(hi));
  }
}

// ---------------- shared pieces ----------------

// copy-staging: A rows 0..29 = [nbr_pk row | edge_pk row], rows 30,31 zero.
// 64 tasks of 512B; task<32: nbr part, task>=32: edge part.
__device__ __forceinline__ void stage_copy(
    const u16* __restrict__ nodes_pk, const u16* __restrict__ edges_pk,
    const int* __restrict__ knn, int n, int t, u16* A)
{
  int w = t >> 6, l = t & 63;
  int sub = l >> 5;                 // 0/1: which of the 2 tasks this issue
  int off = (l & 31) * 8;           // u16 offset within the 256-u16 source row
  #pragma unroll
  for (int j = 0; j < 8; ++j) {
    int task = w * 16 + j * 2 + sub;
    int row  = task & 31;
    int part = task >> 5;           // 0 = nbr, 1 = edge
    int dst = (row * 512 + part * 256 + off) ^ ((row & 7) << 3);
    s16x8 v = {0, 0, 0, 0, 0, 0, 0, 0};
    if (row < KNN) {
      const u16* src = (part == 0)
        ? nodes_pk + (size_t)knn[n * KNN + row] * 256 + off
        : edges_pk + ((size_t)n * KNN + row) * 256 + off;
      v = *(const s16x8*)src;
    }
    *(s16x8*)(A + dst) = v;
  }
}

// MLP1: acc = sp (broadcast over rows) + A @ W1bc, K=256 -> 16 chunks
__device__ __forceinline__ f32x16 mlp1_mfma(
    const u16* A, const u16* __restrict__ pk, float spv, int l)
{
  int lane31 = l & 31, half = l >> 5;
  f32x16 acc;
  #pragma unroll
  for (int r = 0; r < 16; ++r) acc[r] = spv;
  #pragma unroll
  for (int s = 0; s < 16; ++s) {
    s16x8 ah = *(const s16x8*)(A + axi(lane31, s * 32 + half * 8));
    s16x8 al = *(const s16x8*)(A + axi(lane31, s * 32 + 16 + half * 8));
    const u16* pb = pk + (size_t)(s * 2) * 512 + l * 8;
    s16x8 bhv = *(const s16x8*)(pb);
    s16x8 blv = *(const s16x8*)(pb + 512);
    MFMA32(acc, ah, bhv);
    MFMA32(acc, al, bhv);
    MFMA32(acc, ah, blv);
  }
  return acc;
}

// sp = nodes @ W[0:128] + b
__global__ __launch_bounds__(256) void sp_kernel(
    const float* __restrict__ nodes, const float* __restrict__ W,
    const float* __restrict__ b, float* __restrict__ sp)
{
  __shared__ __align__(16) float xl[2][H];
  int n0 = blockIdx.x * 2, t = threadIdx.x;
  int row = t >> 7, col = t & (H - 1);
  xl[row][col] = nodes[(size_t)(n0 + row) * H + col];
  __syncthreads();
  float acc = b[col];
  for (int k = 0; k < H; k += 4) {
    float4 xv = *(const float4*)(&xl[row][k]);
    acc = fmaf(xv.x, W[(k + 0) * H + col], acc);
    acc = fmaf(xv.y, W[(k + 1) * H + col], acc);
    acc = fmaf(xv.z, W[(k + 2) * H + col], acc);
    acc = fmaf(xv.w, W[(k + 3) * H + col], acc);
  }
  sp[(size_t)(n0 + row) * H + col] = acc;
}

// ---------------- per-layer kernels ----------------

__global__ __launch_bounds__(256) void msg_agg_mfma(
    const u16* __restrict__ nodes_pk, const u16* __restrict__ edges_pk,
    const int* __restrict__ knn, const float* __restrict__ sp,
    const u16* __restrict__ pkW1, const float* __restrict__ W2,
    const float* __restrict__ b2, float* __restrict__ agg)
{
  __shared__ __align__(16) u16 A[32 * 512];
  __shared__ __align__(16) float hsum[H];
  int n = blockIdx.x, t = threadIdx.x;
  stage_copy(nodes_pk, edges_pk, knn, n, t, A);
  int w = t >> 6, l = t & 63;
  int lane31 = l & 31, half = l >> 5;
  float spv = sp[(size_t)n * H + w * 32 + lane31];
  __syncthreads();
  f32x16 acc = mlp1_mfma(A, pkW1 + (size_t)(w * 16) * 1024, spv, l);
  // relu + sum over k rows (mask pad rows 30,31 = regs 14,15 on half=1)
  float ss = 0.f;
  #pragma unroll
  for (int r = 0; r < 16; ++r) {
    float v = fmaxf(acc[r], 0.f);
    if (r >= 14) v = half ? 0.f : v;
    ss += v;
  }
  ss += __shfl_xor(ss, 32);
  if (l < 32) hsum[w * 32 + l] = ss;
  __syncthreads();
  if (t < H) {
    float a2 = 0.f;
    for (int k = 0; k < H; k += 4) {
      float4 hv = *(const float4*)(hsum + k);
      a2 = fmaf(hv.x, W2[(k + 0) * H + t], a2);
      a2 = fmaf(hv.y, W2[(k + 1) * H + t], a2);
      a2 = fmaf(hv.z, W2[(k + 2) * H + t], a2);
      a2 = fmaf(hv.w, W2[(k + 3) * H + t], a2);
    }
    agg[(size_t)n * H + t] = a2 + (float)KNN * b2[t];
  }
}

__global__ __launch_bounds__(128) void node_upd_kernel(
    float* __restrict__ nodes, const float* __restrict__ agg,
    const float* __restrict__ W1, const float* __restrict__ b1,
    const float* __restrict__ W2, const float* __restrict__ b2,
    const float* __restrict__ g, const float* __restrict__ bb,
    u16* __restrict__ nodes_pk)
{
  __shared__ __align__(16) float x[2 * H];
  __shared__ __align__(16) float h[H];
  __shared__ float red[2][2];
  int n = blockIdx.x, t = threadIdx.x;
  x[t] = nodes[(size_t)n * H + t];
  x[H + t] = agg[(size_t)n * H + t];
  __syncthreads();
  float acc = 0.f;
  for (int i = 0; i < 2 * H; i += 4) {
    float4 xv = *(const float4*)(x + i);
    acc = fmaf(xv.x, W1[(i + 0) * H + t], acc);
    acc = fmaf(xv.y, W1[(i + 1) * H + t], acc);
    acc = fmaf(xv.z, W1[(i + 2) * H + t], acc);
    acc = fmaf(xv.w, W1[(i + 3) * H + t], acc);
  }
  h[t] = fmaxf(acc + b1[t], 0.f);
  __syncthreads();
  float acc2 = 0.f;
  for (int j = 0; j < H; j += 4) {
    float4 hv = *(const float4*)(h + j);
    acc2 = fmaf(hv.x, W2[(j + 0) * H + t], acc2);
    acc2 = fmaf(hv.y, W2[(j + 1) * H + t], acc2);
    acc2 = fmaf(hv.z, W2[(j + 2) * H + t], acc2);
    acc2 = fmaf(hv.w, W2[(j + 3) * H + t], acc2);
  }
  float y = x[t] + acc2 + b2[t];
  float sum = y, sq = y * y;
  #pragma unroll
  for (int off = 1; off < 64; off <<= 1) {
    sum += __shfl_xor(sum, off);
    sq  += __shfl_xor(sq, off);
  }
  int wv = t >> 6;
  if ((t & 63) == 0) { red[wv][0] = sum; red[wv][1] = sq; }
  __syncthreads();
  float tot = red[0][0] + red[1][0];
  float tsq = red[0][1] + red[1][1];
  float mean = tot * (1.f / (float)H);
  float var  = tsq * (1.f / (float)H) - mean * mean;
  float o = (y - mean) * rsqrtf(var + EPSV) * g[t] + bb[t];
  nodes[(size_t)n * H + t] = o;
  u16 hi = bh(o);
  nodes_pk[(size_t)n * 256 + pko(t)]      = hi;
  nodes_pk[(size_t)n * 256 + pko(t) + 16] = bh(o - hf(hi));
}

__global__ __launch_bounds__(256) void edge_upd_mfma(
    const u16* __restrict__ nodes_pk, u16* __restrict__ edges_pk,
    const int* __restrict__ knn, const float* __restrict__ sp,
    const u16* __restrict__ pkW1, const u16* __restrict__ pkW2,
    const float* __restrict__ b2, const float* __restrict__ g,
    const float* __restrict__ bb)
{
  __shared__ __align__(16) u16 A[32 * 512];     // 32 KB; O aliases after barrier 2
  __shared__ __align__(16) u16 P[32 * 256];     // 16 KB
  __shared__ float mv[32], rs[32];
  float* O = (float*)A;                         // 30 rows x stride 132 f32

  int n = blockIdx.x, t = threadIdx.x;
  stage_copy(nodes_pk, edges_pk, knn, n, t, A);
  int w = t >> 6, l = t & 63;
  int lane31 = l & 31, half = l >> 5;
  int col = w * 32 + lane31;
  float spv = sp[(size_t)n * H + col];
  __syncthreads();                              // 1: A staged
  f32x16 acc = mlp1_mfma(A, pkW1 + (size_t)(w * 16) * 1024, spv, l);
  // residual from staged A (edge part = chunks 8..15): res = hi + lo
  float res[16];
  {
    int coff = 256 + pko(col);
    #pragma unroll
    for (int r = 0; r < 16; ++r) {
      int row = (r & 3) + 8 * (r >> 2) + 4 * half;
      res[r] = (row < KNN)
        ? hf(A[axi(row, coff)]) + hf(A[axi(row, coff + 16)]) : 0.f;
    }
  }
  // P = relu(acc) hi/lo into swizzled LDS (paired cvt_pk)
  {
    int offp = pko(col);
    #pragma unroll
    for (int r = 0; r < 16; r += 2) {
      int row0 = (r & 3) + 8 * (r >> 2) + 4 * half;
      float v0 = fmaxf(acc[r], 0.f), v1 = fmaxf(acc[r + 1], 0.f);
      u32 hp = pk2(v0, v1);
      float l0 = v0 - __uint_as_float(hp << 16);
      float l1 = v1 - __uint_as_float(hp & 0xffff0000u);
      u32 lp = pk2(l0, l1);
      P[pxi(row0, offp)]          = (u16)hp;
      P[pxi(row0, offp + 16)]     = (u16)lp;
      P[pxi(row0 + 1, offp)]      = (u16)(hp >> 16);
      P[pxi(row0 + 1, offp + 16)] = (u16)(lp >> 16);
    }
  }
  __syncthreads();                              // 2: P ready, all A reads done
  // MLP2: a2 = P @ W2 + b2, K=128 -> 8 chunks
  float b2v = b2[col];
  f32x16 a2;
  #pragma unroll
  for (int r = 0; r < 16; ++r) a2[r] = b2v;
  #pragma unroll
  for (int s = 0; s < 8; ++s) {
    s16x8 ah = *(const s16x8*)(P + pxi(lane31, s * 32 + half * 8));
    s16x8 al = *(const s16x8*)(P + pxi(lane31, s * 32 + 16 + half * 8));
    const u16* pb = pkW2 + (size_t)((w * 8 + s) * 2) * 512 + l * 8;
    s16x8 bhv = *(const s16x8*)(pb);
    s16x8 blv = *(const s16x8*)(pb + 512);
    MFMA32(a2, ah, bhv);
    MFMA32(a2, al, bhv);
    MFMA32(a2, ah, blv);
  }
  // y = a2 + residual; O (aliases dead A) for stats
  float y[16];
  #pragma unroll
  for (int r = 0; r < 16; ++r) {
    int row = (r & 3) + 8 * (r >> 2) + 4 * half;
    y[r] = a2[r] + res[r];
    if (row < KNN) O[row * 132 + col] = y[r];
  }
  __syncthreads();                              // 3: O ready
  // stats: 8 threads per row, each sums 16 cols, 3-level shfl combine
  {
    int srow = t >> 3, sub = t & 7;
    if (srow < KNN) {
      const float* Or = O + srow * 132 + sub * 16;
      float s = 0.f, q = 0.f;
      #pragma unroll
      for (int qd = 0; qd < 4; ++qd) {
        float4 v = *(const float4*)(Or + qd * 4);
        s += v.x + v.y + v.z + v.w;
        q = fmaf(v.x, v.x, q); q = fmaf(v.y, v.y, q);
        q = fmaf(v.z, v.z, q); q = fmaf(v.w, v.w, q);
      }
      #pragma unroll
      for (int off = 1; off < 8; off <<= 1) {
        s += __shfl_xor(s, off);
        q += __shfl_xor(q, off);
      }
      if (sub == 0) {
        float mean = s * (1.f / (float)H);
        mv[srow] = mean;
        rs[srow] = rsqrtf(q * (1.f / (float)H) - mean * mean + EPSV);
      }
    }
  }
  __syncthreads();                              // 4: stats ready
  float gv = g[col], bbv = bb[col];
  #pragma unroll
  for (int r = 0; r < 16; r += 2) {
    int row0 = (r & 3) + 8 * (r >> 2) + 4 * half;
    float o0 = (y[r]     - mv[row0])     * rs[row0]     * gv + bbv;
    float o1 = (y[r + 1] - mv[row0 + 1]) * rs[row0 + 1] * gv + bbv;
    u32 hp = pk2(o0, o1);
    float l0 = o0 - __uint_as_float(hp << 16);
    float l1 = o1 - __uint_as_float(hp & 0xffff0000u);
    u32 lp = pk2(l0, l1);
    size_t b0 = ((size_t)n * KNN + row0) * 256 + pko(col);
    if (row0 < KNN) {
      edges_pk[b0]      = (u16)hp;
      edges_pk[b0 + 16] = (u16)lp;
    }
    if (row0 + 1 < KNN) {
      edges_pk[b0 + 256]      = (u16)(hp >> 16);
      edges_pk[b0 + 256 + 16] = (u16)(lp >> 16);
    }
  }
}

// ---------------- output ----------------

__global__ __launch_bounds__(64) void out_kernel(
    const float* __restrict__ nodes, const float* __restrict__ Wout,
    const float* __restrict__ bout, float* __restrict__ out)
{
  __shared__ float x[H];
  int n = blockIdx.x, t = threadIdx.x;
  x[t] = nodes[(size_t)n * H + t];
  x[64 + t] = nodes[(size_t)n * H + 64 + t];
  __syncthreads();
  if (t < AOUT) {
    float acc = bout[t];
    for (int hh = 0; hh < H; ++hh)
      acc = fmaf(x[hh], Wout[hh * AOUT + t], acc);
    out[n * AOUT + t] = acc;
  }
}

// ---------------- launch ----------------

extern "C" void kernel_launch(void* const* d_in, const int* in_sizes, int n_in,
                              void* d_out, int out_size, void* d_ws, size_t ws_size,
                              hipStream_t stream) {
  const float* nf    = (const float*)d_in[0];
  const float* ef    = (const float*)d_in[1];
  const int*   knn   = (const int*)  d_in[2];
  const float* Wn    = (const float*)d_in[3];
  const float* bn    = (const float*)d_in[4];
  const float* We    = (const float*)d_in[5];
  const float* be    = (const float*)d_in[6];
  const float* mW1   = (const float*)d_in[7];
  const float* mb1   = (const float*)d_in[8];
  const float* mW2   = (const float*)d_in[9];
  const float* mb2   = (const float*)d_in[10];
  const float* nW1   = (const float*)d_in[11];
  const float* nb1   = (const float*)d_in[12];
  const float* nW2   = (const float*)d_in[13];
  const float* nb2   = (const float*)d_in[14];
  const float* eW1   = (const float*)d_in[15];
  const float* eb1   = (const float*)d_in[16];
  const float* eW2   = (const float*)d_in[17];
  const float* eb2   = (const float*)d_in[18];
  const float* gn    = (const float*)d_in[19];
  const float* bnrm  = (const float*)d_in[20];
  const float* ge    = (const float*)d_in[21];
  const float* benrm = (const float*)d_in[22];
  const float* Wout  = (const float*)d_in[23];
  const float* bout  = (const float*)d_in[24];
  float* out = (float*)d_out;

  float* ws    = (float*)d_ws;
  float* nodes = ws;                                   // N*H f32
  float* agg   = ws + (size_t)NN * H;                  // N*H f32
  float* sp    = ws + (size_t)2 * NN * H;              // N*H f32
  u16* nodes_pk = (u16*)(ws + (size_t)3 * NN * H);     // N*256 u16 (10 MB)
  u16* edges_pk = nodes_pk + (size_t)NN * 256;         // N*K*256 u16 (307 MB)
  u16* pk       = edges_pk + (size_t)NN * KNN * 256;   // ~1.1 MB packed weights
  u16* pkWe = pk;                       // 4*15*2*512 = 61440
  u16* pkM1 = pkWe + 61440;             // 3 x 65536
  u16* pkE1 = pkM1 + 3 * 65536;         // 3 x 65536
  u16* pkE2 = pkE1 + 3 * 65536;         // 3 x 32768

  node_init_kernel<<<(NN * H + 255) / 256, 256, 0, stream>>>(nf, Wn, bn, nodes, nodes_pk);
  repack_w<<<15, 256, 0, stream>>>(We, pkWe, 15);
  for (int l = 0; l < NL; ++l) {
    repack_w<<<16, 256, 0, stream>>>(mW1 + (size_t)l * CIN * H + 128 * H, pkM1 + l * 65536, 16);
    repack_w<<<16, 256, 0, stream>>>(eW1 + (size_t)l * CIN * H + 128 * H, pkE1 + l * 65536, 16);
    repack_w<<<8,  256, 0, stream>>>(eW2 + (size_t)l * H * H,             pkE2 + l * 32768, 8);
  }
  edge_init_mfma<<<NN * KNN / 32, 256, 0, stream>>>(ef, pkWe, be, edges_pk);

  for (int l = 0; l < NL; ++l) {
    sp_kernel<<<NN / 2, 256, 0, stream>>>(nodes, mW1 + (size_t)l * CIN * H, mb1 + l * H, sp);
    msg_agg_mfma<<<NN, 256, 0, stream>>>(nodes_pk, edges_pk, knn, sp,
        pkM1 + l * 65536, mW2 + (size_t)l * H * H, mb2 + l * H, agg);
    node_upd_kernel<<<NN, 128, 0, stream>>>(nodes, agg,
        nW1 + (size_t)l * 2 * H * H, nb1 + l * H, nW2 + (size_t)l * H * H, nb2 + l * H,
        gn + l * H, bnrm + l * H, nodes_pk);
    sp_kernel<<<NN / 2, 256, 0, stream>>>(nodes, eW1 + (size_t)l * CIN * H, eb1 + l * H, sp);
    edge_upd_mfma<<<NN, 256, 0, stream>>>(nodes_pk, edges_pk, knn, sp,
        pkE1 + l * 65536, pkE2 + l * 32768, eb2 + l * H, ge + l * H, benrm + l * H);
  }
  out_kernel<<<NN, 64, 0, stream>>>(nodes, Wout, bout, out);
}

// Round 7
// 2607.202 us; speedup vs baseline: 7.1661x; 1.1075x over previous
//
#include <hip/hip_runtime.h>

// InverseFoldingModel: 3-layer message-passing GNN, MFMA bf16 hi/lo.
// R7 = R5 exactly, minus the ah*bl MFMA term (2-term: A_full x W_hi).
// Single-variable precision probe + 33% MFMA reduction.

#define NN   20000
#define KNN  30
#define H    128
#define EIN  240
#define NL   3
#define AOUT 20
#define CIN  384   // 2H + E
#define EPSV 1e-5f

typedef unsigned short u16;
typedef unsigned int   u32;
typedef float f32x16 __attribute__((ext_vector_type(16)));
typedef short s16x8  __attribute__((ext_vector_type(8)));
typedef short s16x4  __attribute__((ext_vector_type(4)));

#define MFMA32(acc, a, b) \
  asm("v_mfma_f32_32x32x16_bf16 %0, %1, %2, %0" : "+v"(acc) : "v"(a), "v"(b))

__device__ __forceinline__ u16 bh(float x) {           // f32 -> bf16 (RNE)
  u32 u = __float_as_uint(x);
  u += 0x7fffu + ((u >> 16) & 1u);
  return (u16)(u >> 16);
}
__device__ __forceinline__ float hf(u16 h) { return __uint_as_float(((u32)h) << 16); }
// packed 2x f32 -> 2x bf16 (lo16 = a, hi16 = b)
__device__ __forceinline__ u32 pk2(float a, float b) {
  u32 r; asm("v_cvt_pk_bf16_f32 %0, %1, %2" : "=v"(r) : "v"(a), "v"(b)); return r;
}

// packed-row layout: 128 elems -> 8 chunks x (16 hi u16 + 16 lo u16) = 256 u16
__device__ __forceinline__ int pko(int col) { return ((col >> 4) << 5) + (col & 15); }

// XOR-swizzled LDS indices (u16 units); swizzle: byte ^= (row&7)<<4
__device__ __forceinline__ int axi(int row, int off) { return (row * 512 + off) ^ ((row & 7) << 3); }
__device__ __forceinline__ int pxi(int row, int off) { return (row * 256 + off) ^ ((row & 7) << 3); }

// write 4 consecutive logical-k elements as hi4+lo4 (f32 source; edge_init only)
__device__ __forceinline__ void wrA4(u16* A, int row, int off, float4 v) {
  u16 h0 = bh(v.x), h1 = bh(v.y), h2 = bh(v.z), h3 = bh(v.w);
  s16x4 hv = { (short)h0, (short)h1, (short)h2, (short)h3 };
  s16x4 lv = { (short)bh(v.x - hf(h0)), (short)bh(v.y - hf(h1)),
               (short)bh(v.z - hf(h2)), (short)bh(v.w - hf(h3)) };
  *(s16x4*)(A + axi(row, off))      = hv;
  *(s16x4*)(A + axi(row, off + 16)) = lv;
}

// ---------------- weight repack ----------------
// pk layout: [coltile c<4][chunk s<nS][h<2][lane<64][8 u16]; lane l holds
// W[s*16 + (l>>5)*8 + i][c*32 + (l&31)].
__global__ __launch_bounds__(256) void repack_w(
    const float* __restrict__ W, u16* __restrict__ pk, int nS)
{
  int s = blockIdx.x;
  int t = threadIdx.x;
  int c = t >> 6, l = t & 63;
  int col = c * 32 + (l & 31);
  int kb  = s * 16 + (l >> 5) * 8;
  size_t base = ((size_t)(c * nS + s) * 2) * 512 + l * 8;
  #pragma unroll
  for (int i = 0; i < 8; ++i) {
    float v = W[(size_t)(kb + i) * H + col];
    u16 hi = bh(v);
    pk[base + i]       = hi;
    pk[base + 512 + i] = bh(v - hf(hi));
  }
}

// ---------------- init ----------------

__global__ __launch_bounds__(256) void node_init_kernel(
    const float* __restrict__ nf, const float* __restrict__ Wn,
    const float* __restrict__ bn, float* __restrict__ nodes,
    u16* __restrict__ nodes_pk)
{
  int tid = blockIdx.x * 256 + threadIdx.x;
  if (tid >= NN * H) return;
  int n = tid >> 7, h = tid & (H - 1);
  float acc = bn[h];
  #pragma unroll
  for (int i = 0; i < 6; ++i)
    acc = fmaf(nf[n * 6 + i], Wn[i * H + h], acc);
  nodes[tid] = acc;
  u16 hi = bh(acc);
  nodes_pk[(size_t)n * 256 + pko(h)]      = hi;
  nodes_pk[(size_t)n * 256 + pko(h) + 16] = bh(acc - hf(hi));
}

// edges = ef @ We + be, 32 rows/block via MFMA (K=240 -> 15 chunks), packed output
__global__ __launch_bounds__(256) void edge_init_mfma(
    const float* __restrict__ ef, const u16* __restrict__ pkWe,
    const float* __restrict__ be, u16* __restrict__ edges_pk)
{
  __shared__ __align__(16) u16 A[32 * 512];
  int r0 = blockIdx.x * 32, t = threadIdx.x;
  for (int u = t; u < 1920; u += 256) {
    int r = u & 31, c = u >> 5;                   // c 0..59
    int k = c * 4;
    float4 v = *(const float4*)(ef + (size_t)(r0 + r) * EIN + k);
    wrA4(A, r, (k >> 4) * 32 + (k & 15), v);
  }
  __syncthreads();
  int w = t >> 6, l = t & 63;
  int lane31 = l & 31, half = l >> 5;
  float bev = be[w * 32 + lane31];
  f32x16 acc;
  #pragma unroll
  for (int r = 0; r < 16; ++r) acc[r] = bev;
  #pragma unroll
  for (int s = 0; s < 15; ++s) {
    s16x8 ah = *(const s16x8*)(A + axi(lane31, s * 32 + half * 8));
    s16x8 al = *(const s16x8*)(A + axi(lane31, s * 32 + 16 + half * 8));
    const u16* pb = pkWe + (size_t)((w * 15 + s) * 2) * 512 + l * 8;
    s16x8 bhv = *(const s16x8*)(pb);
    MFMA32(acc, ah, bhv);
    MFMA32(acc, al, bhv);
  }
  int col = w * 32 + lane31;
  #pragma unroll
  for (int r = 0; r < 16; ++r) {
    int row = (r & 3) + 8 * (r >> 2) + 4 * half;
    float v = acc[r];
    u16 hi = bh(v);
    size_t base = (size_t)(r0 + row) * 256 + pko(col);
    edges_pk[base]      = hi;
    edges_pk[base + 16] = bh(v - hf(hi));
  }
}

// ---------------- shared pieces ----------------

// copy-staging: A rows 0..29 = [nbr_pk row | edge_pk row], rows 30,31 zero.
// 64 tasks of 512B; task<32: nbr part, task>=32: edge part.
__device__ __forceinline__ void stage_copy(
    const u16* __restrict__ nodes_pk, const u16* __restrict__ edges_pk,
    const int* __restrict__ knn, int n, int t, u16* A)
{
  int w = t >> 6, l = t & 63;
  int sub = l >> 5;                 // 0/1: which of the 2 tasks this issue
  int off = (l & 31) * 8;           // u16 offset within the 256-u16 source row
  #pragma unroll
  for (int j = 0; j < 8; ++j) {
    int task = w * 16 + j * 2 + sub;
    int row  = task & 31;
    int part = task >> 5;           // 0 = nbr, 1 = edge
    int dst = (row * 512 + part * 256 + off) ^ ((row & 7) << 3);
    s16x8 v = {0, 0, 0, 0, 0, 0, 0, 0};
    if (row < KNN) {
      const u16* src = (part == 0)
        ? nodes_pk + (size_t)knn[n * KNN + row] * 256 + off
        : edges_pk + ((size_t)n * KNN + row) * 256 + off;
      v = *(const s16x8*)src;
    }
    *(s16x8*)(A + dst) = v;
  }
}

// MLP1: acc = sp (broadcast over rows) + A @ W1bc, K=256 -> 16 chunks
// 2-term: (a_hi + a_lo) x W_hi
__device__ __forceinline__ f32x16 mlp1_mfma(
    const u16* A, const u16* __restrict__ pk, float spv, int l)
{
  int lane31 = l & 31, half = l >> 5;
  f32x16 acc;
  #pragma unroll
  for (int r = 0; r < 16; ++r) acc[r] = spv;
  #pragma unroll
  for (int s = 0; s < 16; ++s) {
    s16x8 ah = *(const s16x8*)(A + axi(lane31, s * 32 + half * 8));
    s16x8 al = *(const s16x8*)(A + axi(lane31, s * 32 + 16 + half * 8));
    const u16* pb = pk + (size_t)(s * 2) * 512 + l * 8;
    s16x8 bhv = *(const s16x8*)(pb);
    MFMA32(acc, ah, bhv);
    MFMA32(acc, al, bhv);
  }
  return acc;
}

// sp = nodes @ W[0:128] + b
__global__ __launch_bounds__(256) void sp_kernel(
    const float* __restrict__ nodes, const float* __restrict__ W,
    const float* __restrict__ b, float* __restrict__ sp)
{
  __shared__ __align__(16) float xl[2][H];
  int n0 = blockIdx.x * 2, t = threadIdx.x;
  int row = t >> 7, col = t & (H - 1);
  xl[row][col] = nodes[(size_t)(n0 + row) * H + col];
  __syncthreads();
  float acc = b[col];
  for (int k = 0; k < H; k += 4) {
    float4 xv = *(const float4*)(&xl[row][k]);
    acc = fmaf(xv.x, W[(k + 0) * H + col], acc);
    acc = fmaf(xv.y, W[(k + 1) * H + col], acc);
    acc = fmaf(xv.z, W[(k + 2) * H + col], acc);
    acc = fmaf(xv.w, W[(k + 3) * H + col], acc);
  }
  sp[(size_t)(n0 + row) * H + col] = acc;
}

// ---------------- per-layer kernels ----------------

__global__ __launch_bounds__(256) void msg_agg_mfma(
    const u16* __restrict__ nodes_pk, const u16* __restrict__ edges_pk,
    const int* __restrict__ knn, const float* __restrict__ sp,
    const u16* __restrict__ pkW1, const float* __restrict__ W2,
    const float* __restrict__ b2, float* __restrict__ agg)
{
  __shared__ __align__(16) u16 A[32 * 512];
  __shared__ __align__(16) float hsum[H];
  int n = blockIdx.x, t = threadIdx.x;
  stage_copy(nodes_pk, edges_pk, knn, n, t, A);
  int w = t >> 6, l = t & 63;
  int lane31 = l & 31, half = l >> 5;
  float spv = sp[(size_t)n * H + w * 32 + lane31];
  __syncthreads();
  f32x16 acc = mlp1_mfma(A, pkW1 + (size_t)(w * 16) * 1024, spv, l);
  // relu + sum over k rows (mask pad rows 30,31 = regs 14,15 on half=1)
  float ss = 0.f;
  #pragma unroll
  for (int r = 0; r < 16; ++r) {
    float v = fmaxf(acc[r], 0.f);
    if (r >= 14) v = half ? 0.f : v;
    ss += v;
  }
  ss += __shfl_xor(ss, 32);
  if (l < 32) hsum[w * 32 + l] = ss;
  __syncthreads();
  if (t < H) {
    float a2 = 0.f;
    for (int k = 0; k < H; k += 4) {
      float4 hv = *(const float4*)(hsum + k);
      a2 = fmaf(hv.x, W2[(k + 0) * H + t], a2);
      a2 = fmaf(hv.y, W2[(k + 1) * H + t], a2);
      a2 = fmaf(hv.z, W2[(k + 2) * H + t], a2);
      a2 = fmaf(hv.w, W2[(k + 3) * H + t], a2);
    }
    agg[(size_t)n * H + t] = a2 + (float)KNN * b2[t];
  }
}

__global__ __launch_bounds__(128) void node_upd_kernel(
    float* __restrict__ nodes, const float* __restrict__ agg,
    const float* __restrict__ W1, const float* __restrict__ b1,
    const float* __restrict__ W2, const float* __restrict__ b2,
    const float* __restrict__ g, const float* __restrict__ bb,
    u16* __restrict__ nodes_pk)
{
  __shared__ __align__(16) float x[2 * H];
  __shared__ __align__(16) float h[H];
  __shared__ float red[2][2];
  int n = blockIdx.x, t = threadIdx.x;
  x[t] = nodes[(size_t)n * H + t];
  x[H + t] = agg[(size_t)n * H + t];
  __syncthreads();
  float acc = 0.f;
  for (int i = 0; i < 2 * H; i += 4) {
    float4 xv = *(const float4*)(x + i);
    acc = fmaf(xv.x, W1[(i + 0) * H + t], acc);
    acc = fmaf(xv.y, W1[(i + 1) * H + t], acc);
    acc = fmaf(xv.z, W1[(i + 2) * H + t], acc);
    acc = fmaf(xv.w, W1[(i + 3) * H + t], acc);
  }
  h[t] = fmaxf(acc + b1[t], 0.f);
  __syncthreads();
  float acc2 = 0.f;
  for (int j = 0; j < H; j += 4) {
    float4 hv = *(const float4*)(h + j);
    acc2 = fmaf(hv.x, W2[(j + 0) * H + t], acc2);
    acc2 = fmaf(hv.y, W2[(j + 1) * H + t], acc2);
    acc2 = fmaf(hv.z, W2[(j + 2) * H + t], acc2);
    acc2 = fmaf(hv.w, W2[(j + 3) * H + t], acc2);
  }
  float y = x[t] + acc2 + b2[t];
  float sum = y, sq = y * y;
  #pragma unroll
  for (int off = 1; off < 64; off <<= 1) {
    sum += __shfl_xor(sum, off);
    sq  += __shfl_xor(sq, off);
  }
  int wv = t >> 6;
  if ((t & 63) == 0) { red[wv][0] = sum; red[wv][1] = sq; }
  __syncthreads();
  float tot = red[0][0] + red[1][0];
  float tsq = red[0][1] + red[1][1];
  float mean = tot * (1.f / (float)H);
  float var  = tsq * (1.f / (float)H) - mean * mean;
  float o = (y - mean) * rsqrtf(var + EPSV) * g[t] + bb[t];
  nodes[(size_t)n * H + t] = o;
  u16 hi = bh(o);
  nodes_pk[(size_t)n * 256 + pko(t)]      = hi;
  nodes_pk[(size_t)n * 256 + pko(t) + 16] = bh(o - hf(hi));
}

__global__ __launch_bounds__(256) void edge_upd_mfma(
    const u16* __restrict__ nodes_pk, u16* __restrict__ edges_pk,
    const int* __restrict__ knn, const float* __restrict__ sp,
    const u16* __restrict__ pkW1, const u16* __restrict__ pkW2,
    const float* __restrict__ b2, const float* __restrict__ g,
    const float* __restrict__ bb)
{
  __shared__ __align__(16) u16 A[32 * 512];     // 32 KB; O aliases after barrier 2
  __shared__ __align__(16) u16 P[32 * 256];     // 16 KB
  __shared__ float mv[32], rs[32];
  float* O = (float*)A;                         // 30 rows x stride 132 f32

  int n = blockIdx.x, t = threadIdx.x;
  stage_copy(nodes_pk, edges_pk, knn, n, t, A);
  int w = t >> 6, l = t & 63;
  int lane31 = l & 31, half = l >> 5;
  int col = w * 32 + lane31;
  float spv = sp[(size_t)n * H + col];
  __syncthreads();                              // 1: A staged
  f32x16 acc = mlp1_mfma(A, pkW1 + (size_t)(w * 16) * 1024, spv, l);
  // residual from staged A (edge part = chunks 8..15): res = hi + lo
  float res[16];
  {
    int coff = 256 + pko(col);
    #pragma unroll
    for (int r = 0; r < 16; ++r) {
      int row = (r & 3) + 8 * (r >> 2) + 4 * half;
      res[r] = (row < KNN)
        ? hf(A[axi(row, coff)]) + hf(A[axi(row, coff + 16)]) : 0.f;
    }
  }
  // P = relu(acc) hi/lo into swizzled LDS (paired cvt_pk)
  {
    int offp = pko(col);
    #pragma unroll
    for (int r = 0; r < 16; r += 2) {
      int row0 = (r & 3) + 8 * (r >> 2) + 4 * half;
      float v0 = fmaxf(acc[r], 0.f), v1 = fmaxf(acc[r + 1], 0.f);
      u32 hp = pk2(v0, v1);
      float l0 = v0 - __uint_as_float(hp << 16);
      float l1 = v1 - __uint_as_float(hp & 0xffff0000u);
      u32 lp = pk2(l0, l1);
      P[pxi(row0, offp)]          = (u16)hp;
      P[pxi(row0, offp + 16)]     = (u16)lp;
      P[pxi(row0 + 1, offp)]      = (u16)(hp >> 16);
      P[pxi(row0 + 1, offp + 16)] = (u16)(lp >> 16);
    }
  }
  __syncthreads();                              // 2: P ready, all A reads done
  // MLP2: a2 = P @ W2 + b2, K=128 -> 8 chunks (2-term)
  float b2v = b2[col];
  f32x16 a2;
  #pragma unroll
  for (int r = 0; r < 16; ++r) a2[r] = b2v;
  #pragma unroll
  for (int s = 0; s < 8; ++s) {
    s16x8 ah = *(const s16x8*)(P + pxi(lane31, s * 32 + half * 8));
    s16x8 al = *(const s16x8*)(P + pxi(lane31, s * 32 + 16 + half * 8));
    const u16* pb = pkW2 + (size_t)((w * 8 + s) * 2) * 512 + l * 8;
    s16x8 bhv = *(const s16x8*)(pb);
    MFMA32(a2, ah, bhv);
    MFMA32(a2, al, bhv);
  }
  // y = a2 + residual; O (aliases dead A) for stats
  float y[16];
  #pragma unroll
  for (int r = 0; r < 16; ++r) {
    int row = (r & 3) + 8 * (r >> 2) + 4 * half;
    y[r] = a2[r] + res[r];
    if (row < KNN) O[row * 132 + col] = y[r];
  }
  __syncthreads();                              // 3: O ready
  // stats: 8 threads per row, each sums 16 cols, 3-level shfl combine
  {
    int srow = t >> 3, sub = t & 7;
    if (srow < KNN) {
      const float* Or = O + srow * 132 + sub * 16;
      float s = 0.f, q = 0.f;
      #pragma unroll
      for (int qd = 0; qd < 4; ++qd) {
        float4 v = *(const float4*)(Or + qd * 4);
        s += v.x + v.y + v.z + v.w;
        q = fmaf(v.x, v.x, q); q = fmaf(v.y, v.y, q);
        q = fmaf(v.z, v.z, q); q = fmaf(v.w, v.w, q);
      }
      #pragma unroll
      for (int off = 1; off < 8; off <<= 1) {
        s += __shfl_xor(s, off);
        q += __shfl_xor(q, off);
      }
      if (sub == 0) {
        float mean = s * (1.f / (float)H);
        mv[srow] = mean;
        rs[srow] = rsqrtf(q * (1.f / (float)H) - mean * mean + EPSV);
      }
    }
  }
  __syncthreads();                              // 4: stats ready
  float gv = g[col], bbv = bb[col];
  #pragma unroll
  for (int r = 0; r < 16; r += 2) {
    int row0 = (r & 3) + 8 * (r >> 2) + 4 * half;
    float o0 = (y[r]     - mv[row0])     * rs[row0]     * gv + bbv;
    float o1 = (y[r + 1] - mv[row0 + 1]) * rs[row0 + 1] * gv + bbv;
    u32 hp = pk2(o0, o1);
    float l0 = o0 - __uint_as_float(hp << 16);
    float l1 = o1 - __uint_as_float(hp & 0xffff0000u);
    u32 lp = pk2(l0, l1);
    size_t b0 = ((size_t)n * KNN + row0) * 256 + pko(col);
    if (row0 < KNN) {
      edges_pk[b0]      = (u16)hp;
      edges_pk[b0 + 16] = (u16)lp;
    }
    if (row0 + 1 < KNN) {
      edges_pk[b0 + 256]      = (u16)(hp >> 16);
      edges_pk[b0 + 256 + 16] = (u16)(lp >> 16);
    }
  }
}

// ---------------- output ----------------

__global__ __launch_bounds__(64) void out_kernel(
    const float* __restrict__ nodes, const float* __restrict__ Wout,
    const float* __restrict__ bout, float* __restrict__ out)
{
  __shared__ float x[H];
  int n = blockIdx.x, t = threadIdx.x;
  x[t] = nodes[(size_t)n * H + t];
  x[64 + t] = nodes[(size_t)n * H + 64 + t];
  __syncthreads();
  if (t < AOUT) {
    float acc = bout[t];
    for (int hh = 0; hh < H; ++hh)
      acc = fmaf(x[hh], Wout[hh * AOUT + t], acc);
    out[n * AOUT + t] = acc;
  }
}

// ---------------- launch ----------------

extern "C" void kernel_launch(void* const* d_in, const int* in_sizes, int n_in,
                              void* d_out, int out_size, void* d_ws, size_t ws_size,
                              hipStream_t stream) {
  const float* nf    = (const float*)d_in[0];
  const float* ef    = (const float*)d_in[1];
  const int*   knn   = (const int*)  d_in[2];
  const float* Wn    = (const float*)d_in[3];
  const float* bn    = (const float*)d_in[4];
  const float* We    = (const float*)d_in[5];
  const float* be    = (const float*)d_in[6];
  const float* mW1   = (const float*)d_in[7];
  const float* mb1   = (const float*)d_in[8];
  const float* mW2   = (const float*)d_in[9];
  const float* mb2   = (const float*)d_in[10];
  const float* nW1   = (const float*)d_in[11];
  const float* nb1   = (const float*)d_in[12];
  const float* nW2   = (const float*)d_in[13];
  const float* nb2   = (const float*)d_in[14];
  const float* eW1   = (const float*)d_in[15];
  const float* eb1   = (const float*)d_in[16];
  const float* eW2   = (const float*)d_in[17];
  const float* eb2   = (const float*)d_in[18];
  const float* gn    = (const float*)d_in[19];
  const float* bnrm  = (const float*)d_in[20];
  const float* ge    = (const float*)d_in[21];
  const float* benrm = (const float*)d_in[22];
  const float* Wout  = (const float*)d_in[23];
  const float* bout  = (const float*)d_in[24];
  float* out = (float*)d_out;

  float* ws    = (float*)d_ws;
  float* nodes = ws;                                   // N*H f32
  float* agg   = ws + (size_t)NN * H;                  // N*H f32
  float* sp    = ws + (size_t)2 * NN * H;              // N*H f32
  u16* nodes_pk = (u16*)(ws + (size_t)3 * NN * H);     // N*256 u16 (10 MB)
  u16* edges_pk = nodes_pk + (size_t)NN * 256;         // N*K*256 u16 (307 MB)
  u16* pk       = edges_pk + (size_t)NN * KNN * 256;   // ~1.1 MB packed weights
  u16* pkWe = pk;                       // 4*15*2*512 = 61440
  u16* pkM1 = pkWe + 61440;             // 3 x 65536
  u16* pkE1 = pkM1 + 3 * 65536;         // 3 x 65536
  u16* pkE2 = pkE1 + 3 * 65536;         // 3 x 32768

  node_init_kernel<<<(NN * H + 255) / 256, 256, 0, stream>>>(nf, Wn, bn, nodes, nodes_pk);
  repack_w<<<15, 256, 0, stream>>>(We, pkWe, 15);
  for (int l = 0; l < NL; ++l) {
    repack_w<<<16, 256, 0, stream>>>(mW1 + (size_t)l * CIN * H + 128 * H, pkM1 + l * 65536, 16);
    repack_w<<<16, 256, 0, stream>>>(eW1 + (size_t)l * CIN * H + 128 * H, pkE1 + l * 65536, 16);
    repack_w<<<8,  256, 0, stream>>>(eW2 + (size_t)l * H * H,             pkE2 + l * 32768, 8);
  }
  edge_init_mfma<<<NN * KNN / 32, 256, 0, stream>>>(ef, pkWe, be, edges_pk);

  for (int l = 0; l < NL; ++l) {
    sp_kernel<<<NN / 2, 256, 0, stream>>>(nodes, mW1 + (size_t)l * CIN * H, mb1 + l * H, sp);
    msg_agg_mfma<<<NN, 256, 0, stream>>>(nodes_pk, edges_pk, knn, sp,
        pkM1 + l * 65536, mW2 + (size_t)l * H * H, mb2 + l * H, agg);
    node_upd_kernel<<<NN, 128, 0, stream>>>(nodes, agg,
        nW1 + (size_t)l * 2 * H * H, nb1 + l * H, nW2 + (size_t)l * H * H, nb2 + l * H,
        gn + l * H, bnrm + l * H, nodes_pk);
    sp_kernel<<<NN / 2, 256, 0, stream>>>(nodes, eW1 + (size_t)l * CIN * H, eb1 + l * H, sp);
    edge_upd_mfma<<<NN, 256, 0, stream>>>(nodes_pk, edges_pk, knn, sp,
        pkE1 + l * 65536, pkE2 + l * 32768, eb2 + l * H, ge + l * H, benrm + l * H);
  }
  out_kernel<<<NN, 64, 0, stream>>>(nodes, Wout, bout, out);
}

// Round 8
// 2222.008 us; speedup vs baseline: 8.4083x; 1.1734x over previous
//
#include <hip/hip_runtime.h>

// InverseFoldingModel: 3-layer message-passing GNN, MFMA bf16 hi/lo (2-term).
// R8: skip dead edge_upd(2); fuse edge_upd(l)+msg_agg(l+1) (edge LN result
// written back into LDS A-tile, message MLP1 runs in-block); sp matvecs folded
// into node_upd; fused(1) skips the global edge write. sp_e aliases agg.

#define NN   20000
#define KNN  30
#define H    128
#define EIN  240
#define NL   3
#define AOUT 20
#define CIN  384   // 2H + E
#define EPSV 1e-5f

typedef unsigned short u16;
typedef unsigned int   u32;
typedef float f32x16 __attribute__((ext_vector_type(16)));
typedef short s16x8  __attribute__((ext_vector_type(8)));
typedef short s16x4  __attribute__((ext_vector_type(4)));

#define MFMA32(acc, a, b) \
  asm("v_mfma_f32_32x32x16_bf16 %0, %1, %2, %0" : "+v"(acc) : "v"(a), "v"(b))

__device__ __forceinline__ u16 bh(float x) {           // f32 -> bf16 (RNE)
  u32 u = __float_as_uint(x);
  u += 0x7fffu + ((u >> 16) & 1u);
  return (u16)(u >> 16);
}
__device__ __forceinline__ float hf(u16 h) { return __uint_as_float(((u32)h) << 16); }
// packed 2x f32 -> 2x bf16 (lo16 = a, hi16 = b)
__device__ __forceinline__ u32 pk2(float a, float b) {
  u32 r; asm("v_cvt_pk_bf16_f32 %0, %1, %2" : "=v"(r) : "v"(a), "v"(b)); return r;
}

// packed-row layout: 128 elems -> 8 chunks x (16 hi u16 + 16 lo u16) = 256 u16
__device__ __forceinline__ int pko(int col) { return ((col >> 4) << 5) + (col & 15); }

// XOR-swizzled LDS indices (u16 units); swizzle: byte ^= (row&7)<<4
__device__ __forceinline__ int axi(int row, int off) { return (row * 512 + off) ^ ((row & 7) << 3); }
__device__ __forceinline__ int pxi(int row, int off) { return (row * 256 + off) ^ ((row & 7) << 3); }

// write 4 consecutive logical-k elements as hi4+lo4 (f32 source; edge_init only)
__device__ __forceinline__ void wrA4(u16* A, int row, int off, float4 v) {
  u16 h0 = bh(v.x), h1 = bh(v.y), h2 = bh(v.z), h3 = bh(v.w);
  s16x4 hv = { (short)h0, (short)h1, (short)h2, (short)h3 };
  s16x4 lv = { (short)bh(v.x - hf(h0)), (short)bh(v.y - hf(h1)),
               (short)bh(v.z - hf(h2)), (short)bh(v.w - hf(h3)) };
  *(s16x4*)(A + axi(row, off))      = hv;
  *(s16x4*)(A + axi(row, off + 16)) = lv;
}

// ---------------- weight repack ----------------
// pk layout: [coltile c<4][chunk s<nS][h<2][lane<64][8 u16]
__global__ __launch_bounds__(256) void repack_w(
    const float* __restrict__ W, u16* __restrict__ pk, int nS)
{
  int s = blockIdx.x;
  int t = threadIdx.x;
  int c = t >> 6, l = t & 63;
  int col = c * 32 + (l & 31);
  int kb  = s * 16 + (l >> 5) * 8;
  size_t base = ((size_t)(c * nS + s) * 2) * 512 + l * 8;
  #pragma unroll
  for (int i = 0; i < 8; ++i) {
    float v = W[(size_t)(kb + i) * H + col];
    u16 hi = bh(v);
    pk[base + i]       = hi;
    pk[base + 512 + i] = bh(v - hf(hi));
  }
}

// ---------------- init ----------------

__global__ __launch_bounds__(256) void node_init_kernel(
    const float* __restrict__ nf, const float* __restrict__ Wn,
    const float* __restrict__ bn, float* __restrict__ nodes,
    u16* __restrict__ nodes_pk)
{
  int tid = blockIdx.x * 256 + threadIdx.x;
  if (tid >= NN * H) return;
  int n = tid >> 7, h = tid & (H - 1);
  float acc = bn[h];
  #pragma unroll
  for (int i = 0; i < 6; ++i)
    acc = fmaf(nf[n * 6 + i], Wn[i * H + h], acc);
  nodes[tid] = acc;
  u16 hi = bh(acc);
  nodes_pk[(size_t)n * 256 + pko(h)]      = hi;
  nodes_pk[(size_t)n * 256 + pko(h) + 16] = bh(acc - hf(hi));
}

// edges = ef @ We + be (K=240 -> 15 chunks), packed hi/lo output
__global__ __launch_bounds__(256) void edge_init_mfma(
    const float* __restrict__ ef, const u16* __restrict__ pkWe,
    const float* __restrict__ be, u16* __restrict__ edges_pk)
{
  __shared__ __align__(16) u16 A[32 * 512];
  int r0 = blockIdx.x * 32, t = threadIdx.x;
  for (int u = t; u < 1920; u += 256) {
    int r = u & 31, c = u >> 5;                   // c 0..59
    int k = c * 4;
    float4 v = *(const float4*)(ef + (size_t)(r0 + r) * EIN + k);
    wrA4(A, r, (k >> 4) * 32 + (k & 15), v);
  }
  __syncthreads();
  int w = t >> 6, l = t & 63;
  int lane31 = l & 31, half = l >> 5;
  float bev = be[w * 32 + lane31];
  f32x16 acc;
  #pragma unroll
  for (int r = 0; r < 16; ++r) acc[r] = bev;
  #pragma unroll
  for (int s = 0; s < 15; ++s) {
    s16x8 ah = *(const s16x8*)(A + axi(lane31, s * 32 + half * 8));
    s16x8 al = *(const s16x8*)(A + axi(lane31, s * 32 + 16 + half * 8));
    const u16* pb = pkWe + (size_t)((w * 15 + s) * 2) * 512 + l * 8;
    s16x8 bhv = *(const s16x8*)(pb);
    MFMA32(acc, ah, bhv);
    MFMA32(acc, al, bhv);
  }
  int col = w * 32 + lane31;
  #pragma unroll
  for (int r = 0; r < 16; ++r) {
    int row = (r & 3) + 8 * (r >> 2) + 4 * half;
    float v = acc[r];
    u16 hi = bh(v);
    size_t base = (size_t)(r0 + row) * 256 + pko(col);
    edges_pk[base]      = hi;
    edges_pk[base + 16] = bh(v - hf(hi));
  }
}

// ---------------- shared pieces ----------------

// copy-staging: A rows 0..29 = [nbr_pk row | edge_pk row], rows 30,31 zero.
__device__ __forceinline__ void stage_copy(
    const u16* __restrict__ nodes_pk, const u16* __restrict__ edges_pk,
    const int* __restrict__ knn, int n, int t, u16* A)
{
  int w = t >> 6, l = t & 63;
  int sub = l >> 5;
  int off = (l & 31) * 8;
  #pragma unroll
  for (int j = 0; j < 8; ++j) {
    int task = w * 16 + j * 2 + sub;
    int row  = task & 31;
    int part = task >> 5;           // 0 = nbr, 1 = edge
    int dst = (row * 512 + part * 256 + off) ^ ((row & 7) << 3);
    s16x8 v = {0, 0, 0, 0, 0, 0, 0, 0};
    if (row < KNN) {
      const u16* src = (part == 0)
        ? nodes_pk + (size_t)knn[n * KNN + row] * 256 + off
        : edges_pk + ((size_t)n * KNN + row) * 256 + off;
      v = *(const s16x8*)src;
    }
    *(s16x8*)(A + dst) = v;
  }
}

// MLP1: acc = sp (broadcast over rows) + A @ W1bc, K=256; 2-term (a_hi+a_lo)xW_hi
__device__ __forceinline__ f32x16 mlp1_mfma(
    const u16* A, const u16* __restrict__ pk, float spv, int l)
{
  int lane31 = l & 31, half = l >> 5;
  f32x16 acc;
  #pragma unroll
  for (int r = 0; r < 16; ++r) acc[r] = spv;
  #pragma unroll
  for (int s = 0; s < 16; ++s) {
    s16x8 ah = *(const s16x8*)(A + axi(lane31, s * 32 + half * 8));
    s16x8 al = *(const s16x8*)(A + axi(lane31, s * 32 + 16 + half * 8));
    const u16* pb = pk + (size_t)(s * 2) * 512 + l * 8;
    s16x8 bhv = *(const s16x8*)(pb);
    MFMA32(acc, ah, bhv);
    MFMA32(acc, al, bhv);
  }
  return acc;
}

// sp = nodes @ W[0:128] + b  (only for layer-0 message path)
__global__ __launch_bounds__(256) void sp_kernel(
    const float* __restrict__ nodes, const float* __restrict__ W,
    const float* __restrict__ b, float* __restrict__ sp)
{
  __shared__ __align__(16) float xl[2][H];
  int n0 = blockIdx.x * 2, t = threadIdx.x;
  int row = t >> 7, col = t & (H - 1);
  xl[row][col] = nodes[(size_t)(n0 + row) * H + col];
  __syncthreads();
  float acc = b[col];
  for (int k = 0; k < H; k += 4) {
    float4 xv = *(const float4*)(&xl[row][k]);
    acc = fmaf(xv.x, W[(k + 0) * H + col], acc);
    acc = fmaf(xv.y, W[(k + 1) * H + col], acc);
    acc = fmaf(xv.z, W[(k + 2) * H + col], acc);
    acc = fmaf(xv.w, W[(k + 3) * H + col], acc);
  }
  sp[(size_t)(n0 + row) * H + col] = acc;
}

// ---------------- per-layer kernels ----------------

__global__ __launch_bounds__(256) void msg_agg_mfma(
    const u16* __restrict__ nodes_pk, const u16* __restrict__ edges_pk,
    const int* __restrict__ knn, const float* __restrict__ sp,
    const u16* __restrict__ pkW1, const float* __restrict__ W2,
    const float* __restrict__ b2, float* __restrict__ agg)
{
  __shared__ __align__(16) u16 A[32 * 512];
  __shared__ __align__(16) float hsum[H];
  int n = blockIdx.x, t = threadIdx.x;
  stage_copy(nodes_pk, edges_pk, knn, n, t, A);
  int w = t >> 6, l = t & 63;
  int lane31 = l & 31, half = l >> 5;
  float spv = sp[(size_t)n * H + w * 32 + lane31];
  __syncthreads();
  f32x16 acc = mlp1_mfma(A, pkW1 + (size_t)(w * 16) * 1024, spv, l);
  float ss = 0.f;
  #pragma unroll
  for (int r = 0; r < 16; ++r) {
    float v = fmaxf(acc[r], 0.f);
    if (r >= 14) v = half ? 0.f : v;
    ss += v;
  }
  ss += __shfl_xor(ss, 32);
  if (l < 32) hsum[w * 32 + l] = ss;
  __syncthreads();
  if (t < H) {
    float a2 = 0.f;
    for (int k = 0; k < H; k += 4) {
      float4 hv = *(const float4*)(hsum + k);
      a2 = fmaf(hv.x, W2[(k + 0) * H + t], a2);
      a2 = fmaf(hv.y, W2[(k + 1) * H + t], a2);
      a2 = fmaf(hv.z, W2[(k + 2) * H + t], a2);
      a2 = fmaf(hv.w, W2[(k + 3) * H + t], a2);
    }
    agg[(size_t)n * H + t] = a2 + (float)KNN * b2[t];
  }
}

// node update + LN + fold both sp matvecs (sp_e = newn@eW1src+eb1, sp_m = newn@mW1src+mb1)
__global__ __launch_bounds__(128) void node_upd2_kernel(
    float* __restrict__ nodes, const float* __restrict__ agg,
    const float* __restrict__ W1, const float* __restrict__ b1,
    const float* __restrict__ W2, const float* __restrict__ b2,
    const float* __restrict__ g, const float* __restrict__ bb,
    u16* __restrict__ nodes_pk,
    const float* __restrict__ eW1s, const float* __restrict__ eb1,
    float* __restrict__ sp_e,
    const float* __restrict__ mW1s, const float* __restrict__ mb1,
    float* __restrict__ sp_m)
{
  __shared__ __align__(16) float x[2 * H];
  __shared__ __align__(16) float h[H];
  __shared__ float red[2][2];
  int n = blockIdx.x, t = threadIdx.x;
  x[t] = nodes[(size_t)n * H + t];
  x[H + t] = agg[(size_t)n * H + t];
  __syncthreads();
  float acc = 0.f;
  for (int i = 0; i < 2 * H; i += 4) {
    float4 xv = *(const float4*)(x + i);
    acc = fmaf(xv.x, W1[(i + 0) * H + t], acc);
    acc = fmaf(xv.y, W1[(i + 1) * H + t], acc);
    acc = fmaf(xv.z, W1[(i + 2) * H + t], acc);
    acc = fmaf(xv.w, W1[(i + 3) * H + t], acc);
  }
  h[t] = fmaxf(acc + b1[t], 0.f);
  __syncthreads();
  float acc2 = 0.f;
  for (int j = 0; j < H; j += 4) {
    float4 hv = *(const float4*)(h + j);
    acc2 = fmaf(hv.x, W2[(j + 0) * H + t], acc2);
    acc2 = fmaf(hv.y, W2[(j + 1) * H + t], acc2);
    acc2 = fmaf(hv.z, W2[(j + 2) * H + t], acc2);
    acc2 = fmaf(hv.w, W2[(j + 3) * H + t], acc2);
  }
  float y = x[t] + acc2 + b2[t];
  float sum = y, sq = y * y;
  #pragma unroll
  for (int off = 1; off < 64; off <<= 1) {
    sum += __shfl_xor(sum, off);
    sq  += __shfl_xor(sq, off);
  }
  int wv = t >> 6;
  if ((t & 63) == 0) { red[wv][0] = sum; red[wv][1] = sq; }
  __syncthreads();
  float tot = red[0][0] + red[1][0];
  float tsq = red[0][1] + red[1][1];
  float mean = tot * (1.f / (float)H);
  float var  = tsq * (1.f / (float)H) - mean * mean;
  float o = (y - mean) * rsqrtf(var + EPSV) * g[t] + bb[t];
  nodes[(size_t)n * H + t] = o;
  u16 hi = bh(o);
  nodes_pk[(size_t)n * 256 + pko(t)]      = hi;
  nodes_pk[(size_t)n * 256 + pko(t) + 16] = bh(o - hf(hi));
  __syncthreads();                    // all reads of x done
  x[t] = o;                           // reuse x[0:H] for new node vec
  __syncthreads();
  float ae = eb1[t], am = mb1[t];
  for (int k = 0; k < H; k += 4) {
    float4 xv = *(const float4*)(x + k);
    ae = fmaf(xv.x, eW1s[(k + 0) * H + t], ae);
    ae = fmaf(xv.y, eW1s[(k + 1) * H + t], ae);
    ae = fmaf(xv.z, eW1s[(k + 2) * H + t], ae);
    ae = fmaf(xv.w, eW1s[(k + 3) * H + t], ae);
    am = fmaf(xv.x, mW1s[(k + 0) * H + t], am);
    am = fmaf(xv.y, mW1s[(k + 1) * H + t], am);
    am = fmaf(xv.z, mW1s[(k + 2) * H + t], am);
    am = fmaf(xv.w, mW1s[(k + 3) * H + t], am);
  }
  sp_e[(size_t)n * H + t] = ae;
  sp_m[(size_t)n * H + t] = am;
}

// fused: edge_upd(l) + msg_agg(l+1). New edges written back into the LDS A-tile
// edge half (same swizzled slots staging used), then message MLP1 runs on it.
__global__ __launch_bounds__(256) void fused_edge_msg(
    const u16* __restrict__ nodes_pk, u16* __restrict__ edges_pk,
    const int* __restrict__ knn,
    const float* __restrict__ sp_e, const float* __restrict__ sp_m,
    const u16* __restrict__ pkEW1, const u16* __restrict__ pkEW2,
    const float* __restrict__ eb2, const float* __restrict__ ge,
    const float* __restrict__ gbb,
    const u16* __restrict__ pkMW1, const float* __restrict__ mW2,
    const float* __restrict__ mb2, float* __restrict__ agg,
    int writeEdges)
{
  __shared__ __align__(16) u16 A[32 * 512];     // 32 KB, LIVE throughout
  __shared__ __align__(16) u16 P[32 * 256];     // 16 KB; O aliases after MLP2
  __shared__ __align__(16) float hsum[H];
  __shared__ float mv[32], rs[32];
  float* O = (float*)P;                         // 30 x stride 132 f32 = 15840 B

  int n = blockIdx.x, t = threadIdx.x;
  stage_copy(nodes_pk, edges_pk, knn, n, t, A);
  int w = t >> 6, l = t & 63;
  int lane31 = l & 31, half = l >> 5;
  int col = w * 32 + lane31;
  float spe = sp_e[(size_t)n * H + col];
  float spm = sp_m[(size_t)n * H + col];
  __syncthreads();                              // 1: A staged
  f32x16 acc = mlp1_mfma(A, pkEW1 + (size_t)(w * 16) * 1024, spe, l);
  // residual from staged A edge half
  float res[16];
  {
    int coff = 256 + pko(col);
    #pragma unroll
    for (int r = 0; r < 16; ++r) {
      int row = (r & 3) + 8 * (r >> 2) + 4 * half;
      res[r] = (row < KNN)
        ? hf(A[axi(row, coff)]) + hf(A[axi(row, coff + 16)]) : 0.f;
    }
  }
  // P = relu(acc) hi/lo
  {
    int offp = pko(col);
    #pragma unroll
    for (int r = 0; r < 16; r += 2) {
      int row0 = (r & 3) + 8 * (r >> 2) + 4 * half;
      float v0 = fmaxf(acc[r], 0.f), v1 = fmaxf(acc[r + 1], 0.f);
      u32 hp = pk2(v0, v1);
      float l0 = v0 - __uint_as_float(hp << 16);
      float l1 = v1 - __uint_as_float(hp & 0xffff0000u);
      u32 lp = pk2(l0, l1);
      P[pxi(row0, offp)]          = (u16)hp;
      P[pxi(row0, offp + 16)]     = (u16)lp;
      P[pxi(row0 + 1, offp)]      = (u16)(hp >> 16);
      P[pxi(row0 + 1, offp + 16)] = (u16)(lp >> 16);
    }
  }
  __syncthreads();                              // 2: P ready
  // MLP2: a2 = P @ eW2 + eb2 (2-term)
  float b2v = eb2[col];
  f32x16 a2;
  #pragma unroll
  for (int r = 0; r < 16; ++r) a2[r] = b2v;
  #pragma unroll
  for (int s = 0; s < 8; ++s) {
    s16x8 ah = *(const s16x8*)(P + pxi(lane31, s * 32 + half * 8));
    s16x8 al = *(const s16x8*)(P + pxi(lane31, s * 32 + 16 + half * 8));
    const u16* pb = pkEW2 + (size_t)((w * 8 + s) * 2) * 512 + l * 8;
    s16x8 bhv = *(const s16x8*)(pb);
    MFMA32(a2, ah, bhv);
    MFMA32(a2, al, bhv);
  }
  float y[16];
  #pragma unroll
  for (int r = 0; r < 16; ++r) y[r] = a2[r] + res[r];
  __syncthreads();                              // 3: all P reads done -> O may alias
  #pragma unroll
  for (int r = 0; r < 16; ++r) {
    int row = (r & 3) + 8 * (r >> 2) + 4 * half;
    if (row < KNN) O[row * 132 + col] = y[r];
  }
  __syncthreads();                              // 4: O ready
  {
    int srow = t >> 3, sub = t & 7;
    if (srow < KNN) {
      const float* Or = O + srow * 132 + sub * 16;
      float s = 0.f, q = 0.f;
      #pragma unroll
      for (int qd = 0; qd < 4; ++qd) {
        float4 v = *(const float4*)(Or + qd * 4);
        s += v.x + v.y + v.z + v.w;
        q = fmaf(v.x, v.x, q); q = fmaf(v.y, v.y, q);
        q = fmaf(v.z, v.z, q); q = fmaf(v.w, v.w, q);
      }
      #pragma unroll
      for (int off = 1; off < 8; off <<= 1) {
        s += __shfl_xor(s, off);
        q += __shfl_xor(q, off);
      }
      if (sub == 0) {
        float mean = s * (1.f / (float)H);
        mv[srow] = mean;
        rs[srow] = rsqrtf(q * (1.f / (float)H) - mean * mean + EPSV);
      }
    }
  }
  __syncthreads();                              // 5: stats ready
  // normalize; optional global store; write back into A edge half
  {
    float gv = ge[col], bbv = gbb[col];
    int coff = 256 + pko(col);
    #pragma unroll
    for (int r = 0; r < 16; r += 2) {
      int row0 = (r & 3) + 8 * (r >> 2) + 4 * half;
      float o0 = (y[r]     - mv[row0])     * rs[row0]     * gv + bbv;
      float o1 = (y[r + 1] - mv[row0 + 1]) * rs[row0 + 1] * gv + bbv;
      u32 hp = pk2(o0, o1);
      float l0 = o0 - __uint_as_float(hp << 16);
      float l1 = o1 - __uint_as_float(hp & 0xffff0000u);
      u32 lp = pk2(l0, l1);
      if (writeEdges) {
        size_t b0 = ((size_t)n * KNN + row0) * 256 + pko(col);
        if (row0 < KNN) {
          edges_pk[b0]      = (u16)hp;
          edges_pk[b0 + 16] = (u16)lp;
        }
        if (row0 + 1 < KNN) {
          edges_pk[b0 + 256]      = (u16)(hp >> 16);
          edges_pk[b0 + 256 + 16] = (u16)(lp >> 16);
        }
      }
      if (row0 < KNN) {
        A[axi(row0, coff)]      = (u16)hp;
        A[axi(row0, coff + 16)] = (u16)lp;
      }
      if (row0 + 1 < KNN) {
        A[axi(row0 + 1, coff)]      = (u16)(hp >> 16);
        A[axi(row0 + 1, coff + 16)] = (u16)(lp >> 16);
      }
    }
  }
  __syncthreads();                              // 6: A holds [nbr | new edges]
  // message MLP1 on updated A
  f32x16 macc = mlp1_mfma(A, pkMW1 + (size_t)(w * 16) * 1024, spm, l);
  float ss = 0.f;
  #pragma unroll
  for (int r = 0; r < 16; ++r) {
    float v = fmaxf(macc[r], 0.f);
    if (r >= 14) v = half ? 0.f : v;
    ss += v;
  }
  ss += __shfl_xor(ss, 32);
  if (l < 32) hsum[w * 32 + l] = ss;
  __syncthreads();                              // 7: hsum ready
  if (t < H) {
    float a2m = 0.f;
    for (int k = 0; k < H; k += 4) {
      float4 hv = *(const float4*)(hsum + k);
      a2m = fmaf(hv.x, mW2[(k + 0) * H + t], a2m);
      a2m = fmaf(hv.y, mW2[(k + 1) * H + t], a2m);
      a2m = fmaf(hv.z, mW2[(k + 2) * H + t], a2m);
      a2m = fmaf(hv.w, mW2[(k + 3) * H + t], a2m);
    }
    agg[(size_t)n * H + t] = a2m + (float)KNN * mb2[t];
  }
}

// ---------------- output ----------------

__global__ __launch_bounds__(64) void out_kernel(
    const float* __restrict__ nodes, const float* __restrict__ Wout,
    const float* __restrict__ bout, float* __restrict__ out)
{
  __shared__ float x[H];
  int n = blockIdx.x, t = threadIdx.x;
  x[t] = nodes[(size_t)n * H + t];
  x[64 + t] = nodes[(size_t)n * H + 64 + t];
  __syncthreads();
  if (t < AOUT) {
    float acc = bout[t];
    for (int hh = 0; hh < H; ++hh)
      acc = fmaf(x[hh], Wout[hh * AOUT + t], acc);
    out[n * AOUT + t] = acc;
  }
}

// ---------------- launch ----------------

extern "C" void kernel_launch(void* const* d_in, const int* in_sizes, int n_in,
                              void* d_out, int out_size, void* d_ws, size_t ws_size,
                              hipStream_t stream) {
  const float* nf    = (const float*)d_in[0];
  const float* ef    = (const float*)d_in[1];
  const int*   knn   = (const int*)  d_in[2];
  const float* Wn    = (const float*)d_in[3];
  const float* bn    = (const float*)d_in[4];
  const float* We    = (const float*)d_in[5];
  const float* be    = (const float*)d_in[6];
  const float* mW1   = (const float*)d_in[7];
  const float* mb1   = (const float*)d_in[8];
  const float* mW2   = (const float*)d_in[9];
  const float* mb2   = (const float*)d_in[10];
  const float* nW1   = (const float*)d_in[11];
  const float* nb1   = (const float*)d_in[12];
  const float* nW2   = (const float*)d_in[13];
  const float* nb2   = (const float*)d_in[14];
  const float* eW1   = (const float*)d_in[15];
  const float* eb1   = (const float*)d_in[16];
  const float* eW2   = (const float*)d_in[17];
  const float* eb2   = (const float*)d_in[18];
  const float* gn    = (const float*)d_in[19];
  const float* bnrm  = (const float*)d_in[20];
  const float* ge    = (const float*)d_in[21];
  const float* benrm = (const float*)d_in[22];
  const float* Wout  = (const float*)d_in[23];
  const float* bout  = (const float*)d_in[24];
  float* out = (float*)d_out;

  float* ws     = (float*)d_ws;
  float* nodes  = ws;                                  // N*H f32
  float* aggse  = ws + (size_t)NN * H;                 // N*H f32: agg, aliased by sp_e
  float* sp_m   = ws + (size_t)2 * NN * H;             // N*H f32
  u16* nodes_pk = (u16*)(ws + (size_t)3 * NN * H);     // N*256 u16
  u16* edges_pk = nodes_pk + (size_t)NN * 256;         // N*K*256 u16 (307 MB)
  u16* pk       = edges_pk + (size_t)NN * KNN * 256;   // packed weights
  u16* pkWe = pk;                       // 4*15*2*512 = 61440
  u16* pkM1 = pkWe + 61440;             // 3 x 65536
  u16* pkE1 = pkM1 + 3 * 65536;         // 3 x 65536
  u16* pkE2 = pkE1 + 3 * 65536;         // 3 x 32768
  float* sp_e = aggse;                  // alias: per-block read(sp_e)->write(agg) is safe

  node_init_kernel<<<(NN * H + 255) / 256, 256, 0, stream>>>(nf, Wn, bn, nodes, nodes_pk);
  repack_w<<<15, 256, 0, stream>>>(We, pkWe, 15);
  for (int l = 0; l < NL; ++l) {
    repack_w<<<16, 256, 0, stream>>>(mW1 + (size_t)l * CIN * H + 128 * H, pkM1 + l * 65536, 16);
    repack_w<<<16, 256, 0, stream>>>(eW1 + (size_t)l * CIN * H + 128 * H, pkE1 + l * 65536, 16);
    repack_w<<<8,  256, 0, stream>>>(eW2 + (size_t)l * H * H,             pkE2 + l * 32768, 8);
  }
  edge_init_mfma<<<NN * KNN / 32, 256, 0, stream>>>(ef, pkWe, be, edges_pk);

  // layer-0 message pass (standalone)
  sp_kernel<<<NN / 2, 256, 0, stream>>>(nodes, mW1, mb1, sp_m);
  msg_agg_mfma<<<NN, 256, 0, stream>>>(nodes_pk, edges_pk, knn, sp_m,
      pkM1, mW2, mb2, aggse);

  for (int l = 0; l < NL; ++l) {
    // next-layer mW1 src (dummy = layer 0 for l==2; outputs unused)
    const float* mW1n = (l < 2) ? mW1 + (size_t)(l + 1) * CIN * H : mW1;
    const float* mb1n = (l < 2) ? mb1 + (size_t)(l + 1) * H       : mb1;
    node_upd2_kernel<<<NN, 128, 0, stream>>>(nodes, aggse,
        nW1 + (size_t)l * 2 * H * H, nb1 + l * H,
        nW2 + (size_t)l * H * H, nb2 + l * H,
        gn + l * H, bnrm + l * H, nodes_pk,
        eW1 + (size_t)l * CIN * H, eb1 + l * H, sp_e,
        mW1n, mb1n, sp_m);
    if (l < 2) {
      fused_edge_msg<<<NN, 256, 0, stream>>>(nodes_pk, edges_pk, knn,
          sp_e, sp_m,
          pkE1 + l * 65536, pkE2 + l * 32768, eb2 + l * H,
          ge + l * H, benrm + l * H,
          pkM1 + (l + 1) * 65536, mW2 + (size_t)(l + 1) * H * H,
          mb2 + (l + 1) * H, aggse, (l == 0) ? 1 : 0);
    }
  }
  out_kernel<<<NN, 64, 0, stream>>>(nodes, Wout, bout, out);
}